// Round 7
// baseline (3193.028 us; speedup 1.0000x reference)
//
#include <hip/hip_runtime.h>
#include <hip/hip_bf16.h>

// Leaky tanh RNN, persistent cooperative kernel (round 7: full-M tile + deep pipeline).
// 4 groups x 16 batches (M=16 MFMA fully used), 32 WGs/group = 128 WGs, ONE chain
// per WG. Per WG: wrec[:,32r:32r+32] bf16 hi+lo in LDS, wi slice, wo 2 cols.
// K split across 4 waves, cross-wave LDS reduce.
// Pipeline per step i: g_i frags streamed via per-kt counted vmcnt (issued at
// G(i-1), 1-step flight); x prefetched 2 steps ahead, noise 1 step ahead into
// owner-wave regs (both older than a-loads so vmcnt(7-kt) is uniform); publish
// drain waits only g-store acks; poll read issued before x@wi seed-MFMAs.
// Comm protocol proven in R5: all g/flag ops sc0 sc1 (MALL coherence point),
// stores drained (vmcnt 0) before flag store; no fences, inputs stay cached.

#define T_ 512
#define I_ 128
#define H_ 1024
#define O_ 64
#define GRPS 4
#define BG 16
#define WPG 32
#define NWG 128
#define POLL_CAP (1<<17)

// workspace
#define GBUF_BYTES (GRPS*2*BG*H_*2)      // 262144
#define STEPFLAG_OFF GBUF_BYTES          // u16[4][64] = 512 B
#define WS_NEED (GBUF_BYTES + 1024)

// LDS: weight element offsets (bf16), reduce regions byte offsets
#define WREC_HI_E 0
#define WREC_LO_E 32768
#define WI_HI_E   65536
#define WI_LO_E   69632
#define WO_HI_E   73728      // col-major [2][1024]
#define WO_LO_E   75776
#define RED_B     155648     // [2 nt][3 src][64 lanes][f32x4] = 6144 B
#define REDO_B    161792     // [3 src][8][f32x4] = 384 B
#define LDS_BYTES 162176

typedef __bf16 bf16x8 __attribute__((ext_vector_type(8)));
typedef float f32x4 __attribute__((ext_vector_type(4)));
typedef unsigned u32x4 __attribute__((ext_vector_type(4)));
typedef unsigned short u16;

__device__ __forceinline__ float fast_tanh(float v){
  float cx = fminf(fmaxf(v, -14.f), 14.f);
  float e = __builtin_amdgcn_exp2f(cx * 2.8853900817779268f);
  return 1.f - 2.f * __builtin_amdgcn_rcpf(e + 1.f);
}

// ---- system-scope comm primitives (proven R5/R6) ----
__device__ __forceinline__ void flag_issue(unsigned& v, const u16* p){
  asm volatile("global_load_ushort %0, %1, off sc0 sc1" : "=v"(v) : "v"(p));
}
__device__ __forceinline__ unsigned sflag_load(const u16* p){
  unsigned v;
  asm volatile("global_load_ushort %0, %1, off sc0 sc1\n\ts_waitcnt vmcnt(0)"
               : "=v"(v) : "v"(p) : "memory");
  return v;
}
__device__ __forceinline__ void sflag_store(u16* p, unsigned v){
  asm volatile("global_store_short %0, %1, off sc0 sc1" :: "v"(p), "v"(v) : "memory");
}
__device__ __forceinline__ void g_load_frag(u32x4& d, const u16* p){
  asm volatile("global_load_dwordx4 %0, %1, off sc0 sc1" : "=v"(d) : "v"(p));
}
__device__ __forceinline__ void g_store_u16(u16* p, unsigned v){
  asm volatile("global_store_short %0, %1, off sc0 sc1" :: "v"(p), "v"(v) : "memory");
}
__device__ __forceinline__ void g_store_f32(float* p, float v){
  asm volatile("global_store_dword %0, %1, off" :: "v"(p), "v"(v) : "memory");
}
// plain cached input loads; vmcnt bookkeeping manual
__device__ __forceinline__ void gl_f32x4(f32x4& d, const float* p){
  asm volatile("global_load_dwordx4 %0, %1, off" : "=v"(d) : "v"(p));
}
__device__ __forceinline__ void gl_f32(float& d, const float* p){
  asm volatile("global_load_dword %0, %1, off" : "=v"(d) : "v"(p));
}
// exec barrier + LDS ordering only (vmcnt stays in flight)
__device__ __forceinline__ void barrier_lds(){
  asm volatile("s_waitcnt lgkmcnt(0)\n\ts_barrier" ::: "memory");
}

// [K x 32] col-slice of row-major [K x ld] fp32 -> LDS split bf16 (hi+lo),
// pre-swizzled into MFMA B-frag order (verified rounds 1-6).
__device__ void load_slice(const float* __restrict__ Wg, int ld, int c0, int K,
                           __bf16* hi, __bf16* lo){
  for (int idx = threadIdx.x; idx < K*32; idx += 256){
    int k = idx >> 5, c = idx & 31;
    float v = Wg[(size_t)k*ld + c0 + c];
    __bf16 h = (__bf16)v;
    __bf16 l = (__bf16)(v - (float)h);
    int kt = k >> 5, kin = k & 31, lg = kin >> 3, j = kin & 7;
    int off = (((kt*2 + (c>>4))*64 + (lg*16 + (c&15))) << 3) + j;
    hi[off] = h; lo[off] = l;
  }
}

#define MFMA __builtin_amdgcn_mfma_f32_16x16x32_bf16
#define BC(u) __builtin_bit_cast(bf16x8, u)

// pack two f32x4 into hi/lo bf16x8 A-frags
#define PACKX(v0, v1, xh, xl)                                      \
  { _Pragma("unroll")                                              \
    for (int jj = 0; jj < 4; ++jj){                                \
      float aa = (v0)[jj], bb = (v1)[jj];                          \
      __bf16 ah = (__bf16)aa, bh2 = (__bf16)bb;                    \
      (xh)[jj] = ah; (xh)[jj+4] = bh2;                             \
      (xl)[jj] = (__bf16)(aa - (float)ah);                         \
      (xl)[jj+4] = (__bf16)(bb - (float)bh2); } }

extern "C" __global__ __launch_bounds__(256, 1)
void rnn_kernel(const float* __restrict__ x, const float* __restrict__ noise,
                const float* __restrict__ wi, const float* __restrict__ wrec,
                const float* __restrict__ wo, float* __restrict__ out,
                u16* __restrict__ gbuf, u16* __restrict__ sflags)
{
  extern __shared__ char smem[];
  __bf16* B = (__bf16*)smem;
  float* REDN = (float*)(smem + RED_B);
  float* REDO = (float*)(smem + REDO_B);

  const int grp  = blockIdx.x >> 5;
  const int role = blockIdx.x & 31;
  const int c0 = role * 32;

  load_slice(wrec, H_, c0, H_, B + WREC_HI_E, B + WREC_LO_E);
  load_slice(wi,   H_, c0, I_, B + WI_HI_E,  B + WI_LO_E);
  for (int idx = threadIdx.x; idx < 2*H_; idx += 256){
    int col = idx >> 10, k = idx & (H_-1);
    float v = wo[(size_t)k*O_ + role*2 + col];
    __bf16 hh = (__bf16)v;
    B[WO_HI_E + col*H_ + k] = hh;
    B[WO_LO_E + col*H_ + k] = (__bf16)(v - (float)hh);
  }
  __syncthreads();

  const int lane = threadIdx.x & 63;
  const int w    = threadIdx.x >> 6;   // wave = k-chunk of 256
  const int lhalf = lane >> 4;         // 0..3
  const int l15   = lane & 15;
  const int bf = lane * 8;
  const int wo_off = (l15 & 1)*1024 + lhalf*8;

  u16* gg = gbuf + grp * (2*BG*H_);
  u16* gf = sflags + grp * 64;
  const u16* pollp = gf + lane;                 // 64 flags = role*2+w, w<2
  const u16* abase = gg + (size_t)l15*H_ + w*256 + lhalf*8;   // A row = lane&15

  const float* xrow  = x + (size_t)(grp*BG + l15)*T_*I_ + lhalf*8;
  const float* nrow0 = noise + (size_t)(grp*BG + lhalf*4)*T_*H_ + c0 + (w&1)*16 + l15;
  float* orow = out + (size_t)(grp*BG + lhalf*4)*T_*O_ + role*2 + (l15 & 1);

  f32x4 h0 = {0.f,0.f,0.f,0.f};
  f32x4 xA = {0.f,0.f,0.f,0.f}, xB = {0.f,0.f,0.f,0.f};
  u32x4 a[8];
  f32x4 xv[8];
  float nz[4] = {0.f,0.f,0.f,0.f};

  // ---------------- prologue ----------------
  if (w < 2){
    // x_0 -> seeds_0
    gl_f32x4(xv[0], xrow);      gl_f32x4(xv[1], xrow+4);
    gl_f32x4(xv[2], xrow+32);   gl_f32x4(xv[3], xrow+36);
    gl_f32x4(xv[4], xrow+64);   gl_f32x4(xv[5], xrow+68);
    gl_f32x4(xv[6], xrow+96);   gl_f32x4(xv[7], xrow+100);
    asm volatile("s_waitcnt vmcnt(0)"
      : "+v"(xv[0]),"+v"(xv[1]),"+v"(xv[2]),"+v"(xv[3]),
        "+v"(xv[4]),"+v"(xv[5]),"+v"(xv[6]),"+v"(xv[7]));
    __builtin_amdgcn_sched_barrier(0);
    #pragma unroll
    for (int kt = 0; kt < 4; ++kt){
      bf16x8 xh, xl; PACKX(xv[kt*2], xv[kt*2+1], xh, xl);
      bf16x8 wih = *(const bf16x8*)(B + WI_HI_E + kt*1024 + w*512 + bf);
      bf16x8 wil = *(const bf16x8*)(B + WI_LO_E + kt*1024 + w*512 + bf);
      xA = MFMA(xh, wih, xA, 0,0,0);
      xB = MFMA(xl, wih, xB, 0,0,0);
      xA = MFMA(xh, wil, xA, 0,0,0);
    }
    // issue x_1
    const float* xp = xrow + I_;
    gl_f32x4(xv[0], xp);      gl_f32x4(xv[1], xp+4);
    gl_f32x4(xv[2], xp+32);   gl_f32x4(xv[3], xp+36);
    gl_f32x4(xv[4], xp+64);   gl_f32x4(xv[5], xp+68);
    gl_f32x4(xv[6], xp+96);   gl_f32x4(xv[7], xp+100);
    // issue n_0
    gl_f32(nz[0], nrow0);
    gl_f32(nz[1], nrow0 + (size_t)T_*H_);
    gl_f32(nz[2], nrow0 + (size_t)2*T_*H_);
    gl_f32(nz[3], nrow0 + (size_t)3*T_*H_);
  }
  // a <- g_0 (zeros; parity 0) — MUST be the newest VMEM ops
  #pragma unroll
  for (int kt = 0; kt < 8; ++kt) g_load_frag(a[kt], abase + kt*32);

  // ---------------- main loop ----------------
  for (int i = 0; i < T_; ++i){
    // ---- C: MFMAs, a[kt] streamed via counted vmcnt (a = 8 newest VMEM) ----
    f32x4 c0A={0.f,0.f,0.f,0.f}, c0B={0.f,0.f,0.f,0.f};
    f32x4 c1A={0.f,0.f,0.f,0.f}, c1B={0.f,0.f,0.f,0.f};
    f32x4 oA ={0.f,0.f,0.f,0.f}, oB ={0.f,0.f,0.f,0.f};
    if (w == 0){ c0A = xA; c0B = xB; }
    if (w == 1){ c1A = xA; c1B = xB; }
    const int kb = w*8;
#define CSTEP(KT, N)                                                          \
    { asm volatile("s_waitcnt vmcnt(" #N ")" : "+v"(a[KT]));                  \
      __builtin_amdgcn_sched_barrier(0);                                      \
      const int kg = kb + KT;                                                 \
      bf16x8 av = BC(a[KT]);                                                  \
      bf16x8 bh0 = *(const bf16x8*)(B + WREC_HI_E + kg*1024 + bf);            \
      bf16x8 bl0 = *(const bf16x8*)(B + WREC_LO_E + kg*1024 + bf);            \
      bf16x8 bh1 = *(const bf16x8*)(B + WREC_HI_E + kg*1024 + 512 + bf);      \
      bf16x8 bl1 = *(const bf16x8*)(B + WREC_LO_E + kg*1024 + 512 + bf);      \
      bf16x8 wh  = *(const bf16x8*)(B + WO_HI_E + wo_off + kg*32);            \
      bf16x8 wl  = *(const bf16x8*)(B + WO_LO_E + wo_off + kg*32);            \
      c0A = MFMA(av, bh0, c0A, 0,0,0);  c0B = MFMA(av, bl0, c0B, 0,0,0);      \
      c1A = MFMA(av, bh1, c1A, 0,0,0);  c1B = MFMA(av, bl1, c1B, 0,0,0);      \
      oA  = MFMA(av, wh,  oA,  0,0,0);  oB  = MFMA(av, wl,  oB,  0,0,0); }
    CSTEP(0,7) CSTEP(1,6) CSTEP(2,5) CSTEP(3,4)
    CSTEP(4,3) CSTEP(5,2) CSTEP(6,1) CSTEP(7,0)
#undef CSTEP
    f32x4 cn0 = c0A + c0B, cn1 = c1A + c1B, co = oA + oB;

    // ---- D: cross-wave partials ----
    if (w == 0){ *(f32x4*)&REDN[((1*3+0)*64+lane)*4] = cn1;
                 if (l15 < 2) *(f32x4*)&REDO[(0*8 + lhalf*2 + l15)*4] = co; }
    if (w == 1){ *(f32x4*)&REDN[((0*3+0)*64+lane)*4] = cn0;
                 if (l15 < 2) *(f32x4*)&REDO[(1*8 + lhalf*2 + l15)*4] = co; }
    if (w == 2){ *(f32x4*)&REDN[((0*3+1)*64+lane)*4] = cn0;
                 *(f32x4*)&REDN[((1*3+1)*64+lane)*4] = cn1; }
    if (w == 3){ *(f32x4*)&REDN[((0*3+2)*64+lane)*4] = cn0;
                 *(f32x4*)&REDN[((1*3+2)*64+lane)*4] = cn1;
                 if (l15 < 2) *(f32x4*)&REDO[(2*8 + lhalf*2 + l15)*4] = co; }
    barrier_lds();

    // ---- E: owners reduce + h-update + g stores; w2 writes out[i-1] ----
    if (w < 2){
      const int fb = w ? 3 : 0;
      f32x4 s = w ? cn1 : cn0;
      s += *(f32x4*)&REDN[((fb+0)*64+lane)*4];
      s += *(f32x4*)&REDN[((fb+1)*64+lane)*4];
      s += *(f32x4*)&REDN[((fb+2)*64+lane)*4];
      u16* gp = gg + (size_t)((i+1)&1)*(BG*H_);
      #pragma unroll
      for (int r = 0; r < 4; ++r){
        int row = lhalf*4 + r;                  // 0..15
        float hv = 0.9f*h0[r] + 0.1f*s[r] + 0.002f*nz[r];
        h0[r] = hv;
        u16 gv = __builtin_bit_cast(u16, (__bf16)fast_tanh(hv));
        g_store_u16(gp + (size_t)row*H_ + c0 + w*16 + l15, (unsigned)gv);
      }
    } else if (w == 2 && i > 0 && l15 < 2){
      f32x4 s = co;
      s += *(f32x4*)&REDO[(0*8 + lhalf*2 + l15)*4];
      s += *(f32x4*)&REDO[(1*8 + lhalf*2 + l15)*4];
      s += *(f32x4*)&REDO[(2*8 + lhalf*2 + l15)*4];
      #pragma unroll
      for (int r = 0; r < 4; ++r)
        g_store_f32(orow + (size_t)r*T_*O_ + (size_t)(i-1)*O_, s[r]);
    }

    // ---- F: publish (drain = store acks only; inputs long landed) ----
    if (w < 2){
      asm volatile("s_waitcnt vmcnt(0)" ::: "memory");
      if (lane == 0) sflag_store(gf + role*2 + w, (unsigned)(i+1));
    }

    // ---- G: poll (RT covered by seed MFMAs), then issues ----
    unsigned pv;
    flag_issue(pv, pollp);
    if (w < 2 && i+1 < T_){
      f32x4 nxA = {0.f,0.f,0.f,0.f}, nxB = {0.f,0.f,0.f,0.f};
      #pragma unroll
      for (int kt = 0; kt < 4; ++kt){
        bf16x8 xh, xl; PACKX(xv[kt*2], xv[kt*2+1], xh, xl);
        bf16x8 wih = *(const bf16x8*)(B + WI_HI_E + kt*1024 + w*512 + bf);
        bf16x8 wil = *(const bf16x8*)(B + WI_LO_E + kt*1024 + w*512 + bf);
        nxA = MFMA(xh, wih, nxA, 0,0,0);
        nxB = MFMA(xl, wih, nxB, 0,0,0);
        nxA = MFMA(xh, wil, nxA, 0,0,0);
      }
      xA = nxA; xB = nxB;
    }
    asm volatile("s_waitcnt vmcnt(0)" : "+v"(pv));
    __builtin_amdgcn_sched_barrier(0);
    if (!__all((int)(pv >= (unsigned)(i+1)))){
      int guard = 0;
      while (true){
        unsigned v = sflag_load(pollp);
        if (__all((int)(v >= (unsigned)(i+1)))) break;
        if (++guard > POLL_CAP) break;   // bail: wrong answer beats a hang
      }
    }
    if (w < 2){
      if (i+2 < T_){
        const float* xp = xrow + (size_t)(i+2)*I_;
        gl_f32x4(xv[0], xp);      gl_f32x4(xv[1], xp+4);
        gl_f32x4(xv[2], xp+32);   gl_f32x4(xv[3], xp+36);
        gl_f32x4(xv[4], xp+64);   gl_f32x4(xv[5], xp+68);
        gl_f32x4(xv[6], xp+96);   gl_f32x4(xv[7], xp+100);
      }
      if (i+1 < T_){
        const float* np = nrow0 + (size_t)(i+1)*H_;
        gl_f32(nz[0], np);
        gl_f32(nz[1], np + (size_t)T_*H_);
        gl_f32(nz[2], np + (size_t)2*T_*H_);
        gl_f32(nz[3], np + (size_t)3*T_*H_);
      }
    }
    { // a <- g_{i+1} (parity (i+1)&1) — newest 8 VMEM ops for next C
      const u16* ap = abase + (size_t)((i+1)&1)*(BG*H_);
      #pragma unroll
      for (int kt = 0; kt < 8; ++kt) g_load_frag(a[kt], ap + kt*32);
    }
    barrier_lds();   // RED reuse separation
  }

  // ---------------- epilogue: out[T-1] = g_T @ wo ----------------
  asm volatile("s_waitcnt vmcnt(0)"
    : "+v"(a[0]),"+v"(a[1]),"+v"(a[2]),"+v"(a[3]),
      "+v"(a[4]),"+v"(a[5]),"+v"(a[6]),"+v"(a[7]));
  __builtin_amdgcn_sched_barrier(0);
  {
    f32x4 oA={0.f,0.f,0.f,0.f}, oB={0.f,0.f,0.f,0.f};
    const int kb = w*8;
    #pragma unroll
    for (int kt = 0; kt < 8; ++kt){
      const int kg = kb + kt;
      bf16x8 wh = *(const bf16x8*)(B + WO_HI_E + wo_off + kg*32);
      bf16x8 wl = *(const bf16x8*)(B + WO_LO_E + wo_off + kg*32);
      bf16x8 av = BC(a[kt]);
      oA = MFMA(av, wh, oA, 0,0,0);  oB = MFMA(av, wl, oB, 0,0,0);
    }
    f32x4 co = oA + oB;
    if (l15 < 2){
      if (w == 0) *(f32x4*)&REDO[(0*8 + lhalf*2 + l15)*4] = co;
      if (w == 1) *(f32x4*)&REDO[(1*8 + lhalf*2 + l15)*4] = co;
      if (w == 3) *(f32x4*)&REDO[(2*8 + lhalf*2 + l15)*4] = co;
    }
    barrier_lds();
    if (w == 2 && l15 < 2){
      f32x4 s = co;
      s += *(f32x4*)&REDO[(0*8 + lhalf*2 + l15)*4];
      s += *(f32x4*)&REDO[(1*8 + lhalf*2 + l15)*4];
      s += *(f32x4*)&REDO[(2*8 + lhalf*2 + l15)*4];
      #pragma unroll
      for (int r = 0; r < 4; ++r)
        g_store_f32(orow + (size_t)r*T_*O_ + (size_t)(T_-1)*O_, s[r]);
    }
  }
  asm volatile("s_waitcnt vmcnt(0)" ::: "memory");
}

extern "C" void kernel_launch(void* const* d_in, const int* in_sizes, int n_in,
                              void* d_out, int out_size, void* d_ws, size_t ws_size,
                              hipStream_t stream){
  const float* x     = (const float*)d_in[0];
  const float* noise = (const float*)d_in[1];
  const float* wi    = (const float*)d_in[2];
  const float* wrec  = (const float*)d_in[3];
  const float* wo    = (const float*)d_in[4];
  float* out = (float*)d_out;

  if (ws_size < (size_t)WS_NEED) return;
  u16* gbuf = (u16*)d_ws;
  u16* sflags = (u16*)((char*)d_ws + STEPFLAG_OFF);

  hipMemsetAsync(d_ws, 0, WS_NEED, stream);   // zero g_0 + flags

  hipFuncSetAttribute((const void*)rnn_kernel,
                      hipFuncAttributeMaxDynamicSharedMemorySize, LDS_BYTES);

  void* args[] = {(void*)&x, (void*)&noise, (void*)&wi, (void*)&wrec, (void*)&wo,
                  (void*)&out, (void*)&gbuf, (void*)&sflags};
  hipLaunchCooperativeKernel((const void*)rnn_kernel, dim3(NWG), dim3(256),
                             args, LDS_BYTES, stream);
}

// Round 8
// 3182.210 us; speedup vs baseline: 1.0034x; 1.0034x over previous
//
#include <hip/hip_runtime.h>
#include <hip/hip_bf16.h>

// Leaky tanh RNN, persistent cooperative kernel (round 8: MALL-atomic publish).
// 4 groups x 16 batches, 32 WGs/group = 128 WGs, one chain per WG.
// WG role r owns wrec[:,32r:32r+32] bf16 hi+lo in LDS + wi slice + wo 2 cols;
// K split across 4 waves, cross-wave LDS reduce.
// Protocol change vs R7 (which wrote g via sc0sc1 write-through to HBM and ate
// an HBM-depth store-ack drain every step, WRITE_SIZE=100MB):
//   - g published as packed u32 global_atomic_swap (2 bf16/dword, executes at
//     the MALL coherence point; ack does not wait for HBM write-through)
//   - flags are u32 global_atomic_swap; consumers poll with sc0sc1 loads
//   - per-wave flag subsets: wave w needs only roles 8w..8w+7 -> 16 flags (64B)
//   - RED-reuse barrier moved to E->F so poll/issue/MFMA of different waves
//     overlap (absorbs inter-wave skew)
// Reads of g stay sc0sc1 (L2-bypass -> MALL). Inputs x/noise stay cached.

#define T_ 512
#define I_ 128
#define H_ 1024
#define O_ 64
#define GRPS 4
#define BG 16
#define WPG 32
#define NWG 128
#define POLL_CAP (1<<17)

// workspace
#define GBUF_BYTES (GRPS*2*BG*H_*2)      // 262144
#define STEPFLAG_OFF GBUF_BYTES          // u32[4][64] = 1024 B
#define WS_NEED (GBUF_BYTES + 1024)

// LDS: weight element offsets (bf16), reduce regions byte offsets
#define WREC_HI_E 0
#define WREC_LO_E 32768
#define WI_HI_E   65536
#define WI_LO_E   69632
#define WO_HI_E   73728      // col-major [2][1024]
#define WO_LO_E   75776
#define RED_B     155648     // [2 nt][3 src][64 lanes][f32x4] = 6144 B
#define REDO_B    161792     // [3 src][8][f32x4] = 384 B
#define LDS_BYTES 162176

typedef __bf16 bf16x8 __attribute__((ext_vector_type(8)));
typedef float f32x4 __attribute__((ext_vector_type(4)));
typedef unsigned u32x4 __attribute__((ext_vector_type(4)));
typedef unsigned short u16;

__device__ __forceinline__ float fast_tanh(float v){
  float cx = fminf(fmaxf(v, -14.f), 14.f);
  float e = __builtin_amdgcn_exp2f(cx * 2.8853900817779268f);
  return 1.f - 2.f * __builtin_amdgcn_rcpf(e + 1.f);
}

// ---- comm primitives ----
__device__ __forceinline__ void flag_issue(unsigned& v, const unsigned* p){
  asm volatile("global_load_dword %0, %1, off sc0 sc1" : "=v"(v) : "v"(p));
}
__device__ __forceinline__ unsigned flag_load(const unsigned* p){
  unsigned v;
  asm volatile("global_load_dword %0, %1, off sc0 sc1\n\ts_waitcnt vmcnt(0)"
               : "=v"(v) : "v"(p) : "memory");
  return v;
}
__device__ __forceinline__ void atom_swap_u32(unsigned* p, unsigned v){
  asm volatile("global_atomic_swap %0, %1, off" :: "v"(p), "v"(v) : "memory");
}
__device__ __forceinline__ void g_load_frag(u32x4& d, const u16* p){
  asm volatile("global_load_dwordx4 %0, %1, off sc0 sc1" : "=v"(d) : "v"(p));
}
__device__ __forceinline__ void g_store_f32(float* p, float v){
  asm volatile("global_store_dword %0, %1, off" :: "v"(p), "v"(v) : "memory");
}
// plain cached input loads; vmcnt bookkeeping manual
__device__ __forceinline__ void gl_f32x4(f32x4& d, const float* p){
  asm volatile("global_load_dwordx4 %0, %1, off" : "=v"(d) : "v"(p));
}
__device__ __forceinline__ void gl_f32(float& d, const float* p){
  asm volatile("global_load_dword %0, %1, off" : "=v"(d) : "v"(p));
}
// exec barrier + LDS ordering only (vmcnt stays in flight)
__device__ __forceinline__ void barrier_lds(){
  asm volatile("s_waitcnt lgkmcnt(0)\n\ts_barrier" ::: "memory");
}

// [K x 32] col-slice of row-major [K x ld] fp32 -> LDS split bf16 (hi+lo),
// pre-swizzled into MFMA B-frag order (verified rounds 1-7).
__device__ void load_slice(const float* __restrict__ Wg, int ld, int c0, int K,
                           __bf16* hi, __bf16* lo){
  for (int idx = threadIdx.x; idx < K*32; idx += 256){
    int k = idx >> 5, c = idx & 31;
    float v = Wg[(size_t)k*ld + c0 + c];
    __bf16 h = (__bf16)v;
    __bf16 l = (__bf16)(v - (float)h);
    int kt = k >> 5, kin = k & 31, lg = kin >> 3, j = kin & 7;
    int off = (((kt*2 + (c>>4))*64 + (lg*16 + (c&15))) << 3) + j;
    hi[off] = h; lo[off] = l;
  }
}

#define MFMA __builtin_amdgcn_mfma_f32_16x16x32_bf16
#define BC(u) __builtin_bit_cast(bf16x8, u)

#define PACKX(v0, v1, xh, xl)                                      \
  { _Pragma("unroll")                                              \
    for (int jj = 0; jj < 4; ++jj){                                \
      float aa = (v0)[jj], bb = (v1)[jj];                          \
      __bf16 ah = (__bf16)aa, bh2 = (__bf16)bb;                    \
      (xh)[jj] = ah; (xh)[jj+4] = bh2;                             \
      (xl)[jj] = (__bf16)(aa - (float)ah);                         \
      (xl)[jj+4] = (__bf16)(bb - (float)bh2); } }

extern "C" __global__ __launch_bounds__(256, 1)
void rnn_kernel(const float* __restrict__ x, const float* __restrict__ noise,
                const float* __restrict__ wi, const float* __restrict__ wrec,
                const float* __restrict__ wo, float* __restrict__ out,
                u16* __restrict__ gbuf, unsigned* __restrict__ flags)
{
  extern __shared__ char smem[];
  __bf16* B = (__bf16*)smem;
  float* REDN = (float*)(smem + RED_B);
  float* REDO = (float*)(smem + REDO_B);

  const int grp  = blockIdx.x >> 5;
  const int role = blockIdx.x & 31;
  const int c0 = role * 32;

  load_slice(wrec, H_, c0, H_, B + WREC_HI_E, B + WREC_LO_E);
  load_slice(wi,   H_, c0, I_, B + WI_HI_E,  B + WI_LO_E);
  for (int idx = threadIdx.x; idx < 2*H_; idx += 256){
    int col = idx >> 10, k = idx & (H_-1);
    float v = wo[(size_t)k*O_ + role*2 + col];
    __bf16 hh = (__bf16)v;
    B[WO_HI_E + col*H_ + k] = hh;
    B[WO_LO_E + col*H_ + k] = (__bf16)(v - (float)hh);
  }
  __syncthreads();

  const int lane = threadIdx.x & 63;
  const int w    = threadIdx.x >> 6;   // wave = k-chunk of 256
  const int lhalf = lane >> 4;         // 0..3
  const int l15   = lane & 15;
  const int bf = lane * 8;
  const int wo_off = (l15 & 1)*1024 + lhalf*8;

  u16* gg = gbuf + grp * (2*BG*H_);
  unsigned* gfl = flags + grp * 64;
  // wave w consumes k in [256w, 256w+256) -> producer roles 8w..8w+7 -> flags 16w..16w+15
  const unsigned* pollp = gfl + w*16 + (lane & 15);
  unsigned* myflag = gfl + role*2 + w;   // producers: w<2
  const u16* abase = gg + (size_t)l15*H_ + w*256 + lhalf*8;   // A row = lane&15

  const float* xrow  = x + (size_t)(grp*BG + l15)*T_*I_ + lhalf*8;
  const float* nrow0 = noise + (size_t)(grp*BG + lhalf*4)*T_*H_ + c0 + (w&1)*16 + l15;
  float* orow = out + (size_t)(grp*BG + lhalf*4)*T_*O_ + role*2 + (l15 & 1);

  f32x4 h0 = {0.f,0.f,0.f,0.f};
  f32x4 xA = {0.f,0.f,0.f,0.f}, xB = {0.f,0.f,0.f,0.f};
  u32x4 a[8];
  f32x4 xv[8];
  float nz[4] = {0.f,0.f,0.f,0.f};

  // ---------------- prologue ----------------
  if (w < 2){
    gl_f32x4(xv[0], xrow);      gl_f32x4(xv[1], xrow+4);
    gl_f32x4(xv[2], xrow+32);   gl_f32x4(xv[3], xrow+36);
    gl_f32x4(xv[4], xrow+64);   gl_f32x4(xv[5], xrow+68);
    gl_f32x4(xv[6], xrow+96);   gl_f32x4(xv[7], xrow+100);
    asm volatile("s_waitcnt vmcnt(0)"
      : "+v"(xv[0]),"+v"(xv[1]),"+v"(xv[2]),"+v"(xv[3]),
        "+v"(xv[4]),"+v"(xv[5]),"+v"(xv[6]),"+v"(xv[7]));
    __builtin_amdgcn_sched_barrier(0);
    #pragma unroll
    for (int kt = 0; kt < 4; ++kt){
      bf16x8 xh, xl; PACKX(xv[kt*2], xv[kt*2+1], xh, xl);
      bf16x8 wih = *(const bf16x8*)(B + WI_HI_E + kt*1024 + w*512 + bf);
      bf16x8 wil = *(const bf16x8*)(B + WI_LO_E + kt*1024 + w*512 + bf);
      xA = MFMA(xh, wih, xA, 0,0,0);
      xB = MFMA(xl, wih, xB, 0,0,0);
      xA = MFMA(xh, wil, xA, 0,0,0);
    }
    const float* xp = xrow + I_;
    gl_f32x4(xv[0], xp);      gl_f32x4(xv[1], xp+4);
    gl_f32x4(xv[2], xp+32);   gl_f32x4(xv[3], xp+36);
    gl_f32x4(xv[4], xp+64);   gl_f32x4(xv[5], xp+68);
    gl_f32x4(xv[6], xp+96);   gl_f32x4(xv[7], xp+100);
    gl_f32(nz[0], nrow0);
    gl_f32(nz[1], nrow0 + (size_t)T_*H_);
    gl_f32(nz[2], nrow0 + (size_t)2*T_*H_);
    gl_f32(nz[3], nrow0 + (size_t)3*T_*H_);
  }
  // a <- g_0 (zeros; parity 0) — newest VMEM ops
  #pragma unroll
  for (int kt = 0; kt < 8; ++kt) g_load_frag(a[kt], abase + kt*32);

  // ---------------- main loop ----------------
  for (int i = 0; i < T_; ++i){
    // ---- C: MFMAs, a[kt] streamed via counted vmcnt (a = 8 newest VMEM) ----
    f32x4 c0A={0.f,0.f,0.f,0.f}, c0B={0.f,0.f,0.f,0.f};
    f32x4 c1A={0.f,0.f,0.f,0.f}, c1B={0.f,0.f,0.f,0.f};
    f32x4 oA ={0.f,0.f,0.f,0.f}, oB ={0.f,0.f,0.f,0.f};
    if (w == 0){ c0A = xA; c0B = xB; }
    if (w == 1){ c1A = xA; c1B = xB; }
    const int kb = w*8;
#define CSTEP(KT, N)                                                          \
    { asm volatile("s_waitcnt vmcnt(" #N ")" : "+v"(a[KT]));                  \
      __builtin_amdgcn_sched_barrier(0);                                      \
      const int kg = kb + KT;                                                 \
      bf16x8 av = BC(a[KT]);                                                  \
      bf16x8 bh0 = *(const bf16x8*)(B + WREC_HI_E + kg*1024 + bf);            \
      bf16x8 bl0 = *(const bf16x8*)(B + WREC_LO_E + kg*1024 + bf);            \
      bf16x8 bh1 = *(const bf16x8*)(B + WREC_HI_E + kg*1024 + 512 + bf);      \
      bf16x8 bl1 = *(const bf16x8*)(B + WREC_LO_E + kg*1024 + 512 + bf);      \
      bf16x8 wh  = *(const bf16x8*)(B + WO_HI_E + wo_off + kg*32);            \
      bf16x8 wl  = *(const bf16x8*)(B + WO_LO_E + wo_off + kg*32);            \
      c0A = MFMA(av, bh0, c0A, 0,0,0);  c0B = MFMA(av, bl0, c0B, 0,0,0);      \
      c1A = MFMA(av, bh1, c1A, 0,0,0);  c1B = MFMA(av, bl1, c1B, 0,0,0);      \
      oA  = MFMA(av, wh,  oA,  0,0,0);  oB  = MFMA(av, wl,  oB,  0,0,0); }
    CSTEP(0,7) CSTEP(1,6) CSTEP(2,5) CSTEP(3,4)
    CSTEP(4,3) CSTEP(5,2) CSTEP(6,1) CSTEP(7,0)
#undef CSTEP
    f32x4 cn0 = c0A + c0B, cn1 = c1A + c1B, co = oA + oB;

    // ---- D: cross-wave partials ----
    if (w == 0){ *(f32x4*)&REDN[((1*3+0)*64+lane)*4] = cn1;
                 if (l15 < 2) *(f32x4*)&REDO[(0*8 + lhalf*2 + l15)*4] = co; }
    if (w == 1){ *(f32x4*)&REDN[((0*3+0)*64+lane)*4] = cn0;
                 if (l15 < 2) *(f32x4*)&REDO[(1*8 + lhalf*2 + l15)*4] = co; }
    if (w == 2){ *(f32x4*)&REDN[((0*3+1)*64+lane)*4] = cn0;
                 *(f32x4*)&REDN[((1*3+1)*64+lane)*4] = cn1; }
    if (w == 3){ *(f32x4*)&REDN[((0*3+2)*64+lane)*4] = cn0;
                 *(f32x4*)&REDN[((1*3+2)*64+lane)*4] = cn1;
                 if (l15 < 2) *(f32x4*)&REDO[(2*8 + lhalf*2 + l15)*4] = co; }
    barrier_lds();

    // ---- E: owners reduce + h-update + packed atomic g publish; w2 out ----
    if (w < 2){
      const int fb = w ? 3 : 0;
      f32x4 s = w ? cn1 : cn0;
      s += *(f32x4*)&REDN[((fb+0)*64+lane)*4];
      s += *(f32x4*)&REDN[((fb+1)*64+lane)*4];
      s += *(f32x4*)&REDN[((fb+2)*64+lane)*4];
      u16* gp = gg + (size_t)((i+1)&1)*(BG*H_);
      unsigned pk[4];
      #pragma unroll
      for (int r = 0; r < 4; ++r){
        float hv = 0.9f*h0[r] + 0.1f*s[r] + 0.002f*nz[r];
        h0[r] = hv;
        unsigned gv = (unsigned)__builtin_bit_cast(u16, (__bf16)fast_tanh(hv));
        unsigned pg = (unsigned)__shfl_xor((int)gv, 1);   // partner col's bf16
        pk[r] = gv | (pg << 16);                          // even lane: (c, c+1)
      }
      if (!(l15 & 1)){
        #pragma unroll
        for (int r = 0; r < 4; ++r){
          int row = lhalf*4 + r;
          atom_swap_u32((unsigned*)(gp + (size_t)row*H_ + c0 + w*16 + l15), pk[r]);
        }
      }
    } else if (w == 2 && i > 0 && l15 < 2){
      f32x4 s = co;
      s += *(f32x4*)&REDO[(0*8 + lhalf*2 + l15)*4];
      s += *(f32x4*)&REDO[(1*8 + lhalf*2 + l15)*4];
      s += *(f32x4*)&REDO[(2*8 + lhalf*2 + l15)*4];
      #pragma unroll
      for (int r = 0; r < 4; ++r)
        g_store_f32(orow + (size_t)r*T_*O_ + (size_t)(i-1)*O_, s[r]);
    }
    barrier_lds();   // E -> D' separation (moved from loop end: polls overlap)

    // ---- F: publish flag (drain = atomic acks from MALL, not HBM) ----
    if (w < 2){
      asm volatile("s_waitcnt vmcnt(0)" ::: "memory");
      if (lane == 0) atom_swap_u32(myflag, (unsigned)(i+1));
    }

    // ---- G: poll own producer octet (RT covered by seed MFMAs), issues ----
    unsigned pv;
    flag_issue(pv, pollp);
    if (w < 2 && i+1 < T_){
      f32x4 nxA = {0.f,0.f,0.f,0.f}, nxB = {0.f,0.f,0.f,0.f};
      #pragma unroll
      for (int kt = 0; kt < 4; ++kt){
        bf16x8 xh, xl; PACKX(xv[kt*2], xv[kt*2+1], xh, xl);
        bf16x8 wih = *(const bf16x8*)(B + WI_HI_E + kt*1024 + w*512 + bf);
        bf16x8 wil = *(const bf16x8*)(B + WI_LO_E + kt*1024 + w*512 + bf);
        nxA = MFMA(xh, wih, nxA, 0,0,0);
        nxB = MFMA(xl, wih, nxB, 0,0,0);
        nxA = MFMA(xh, wil, nxA, 0,0,0);
      }
      xA = nxA; xB = nxB;
    }
    asm volatile("s_waitcnt vmcnt(0)" : "+v"(pv));
    __builtin_amdgcn_sched_barrier(0);
    if (!__all((int)(pv >= (unsigned)(i+1)))){
      int guard = 0;
      while (true){
        unsigned v = flag_load(pollp);
        if (__all((int)(v >= (unsigned)(i+1)))) break;
        if (++guard > POLL_CAP) break;   // bail: wrong answer beats a hang
      }
    }
    if (w < 2){
      if (i+2 < T_){
        const float* xp = xrow + (size_t)(i+2)*I_;
        gl_f32x4(xv[0], xp);      gl_f32x4(xv[1], xp+4);
        gl_f32x4(xv[2], xp+32);   gl_f32x4(xv[3], xp+36);
        gl_f32x4(xv[4], xp+64);   gl_f32x4(xv[5], xp+68);
        gl_f32x4(xv[6], xp+96);   gl_f32x4(xv[7], xp+100);
      }
      if (i+1 < T_){
        const float* np = nrow0 + (size_t)(i+1)*H_;
        gl_f32(nz[0], np);
        gl_f32(nz[1], np + (size_t)T_*H_);
        gl_f32(nz[2], np + (size_t)2*T_*H_);
        gl_f32(nz[3], np + (size_t)3*T_*H_);
      }
    }
    { // a <- g_{i+1} (parity (i+1)&1) — newest 8 VMEM ops for next C
      const u16* ap = abase + (size_t)((i+1)&1)*(BG*H_);
      #pragma unroll
      for (int kt = 0; kt < 8; ++kt) g_load_frag(a[kt], ap + kt*32);
    }
  }

  // ---------------- epilogue: out[T-1] = g_T @ wo ----------------
  asm volatile("s_waitcnt vmcnt(0)"
    : "+v"(a[0]),"+v"(a[1]),"+v"(a[2]),"+v"(a[3]),
      "+v"(a[4]),"+v"(a[5]),"+v"(a[6]),"+v"(a[7]));
  __builtin_amdgcn_sched_barrier(0);
  {
    f32x4 oA={0.f,0.f,0.f,0.f}, oB={0.f,0.f,0.f,0.f};
    const int kb = w*8;
    #pragma unroll
    for (int kt = 0; kt < 8; ++kt){
      const int kg = kb + kt;
      bf16x8 wh = *(const bf16x8*)(B + WO_HI_E + wo_off + kg*32);
      bf16x8 wl = *(const bf16x8*)(B + WO_LO_E + wo_off + kg*32);
      bf16x8 av = BC(a[kt]);
      oA = MFMA(av, wh, oA, 0,0,0);  oB = MFMA(av, wl, oB, 0,0,0);
    }
    f32x4 co = oA + oB;
    barrier_lds();   // last loop E readers done before REDO reuse
    if (l15 < 2){
      if (w == 0) *(f32x4*)&REDO[(0*8 + lhalf*2 + l15)*4] = co;
      if (w == 1) *(f32x4*)&REDO[(1*8 + lhalf*2 + l15)*4] = co;
      if (w == 3) *(f32x4*)&REDO[(2*8 + lhalf*2 + l15)*4] = co;
    }
    barrier_lds();
    if (w == 2 && l15 < 2){
      f32x4 s = co;
      s += *(f32x4*)&REDO[(0*8 + lhalf*2 + l15)*4];
      s += *(f32x4*)&REDO[(1*8 + lhalf*2 + l15)*4];
      s += *(f32x4*)&REDO[(2*8 + lhalf*2 + l15)*4];
      #pragma unroll
      for (int r = 0; r < 4; ++r)
        g_store_f32(orow + (size_t)r*T_*O_ + (size_t)(T_-1)*O_, s[r]);
    }
  }
  asm volatile("s_waitcnt vmcnt(0)" ::: "memory");
}

extern "C" void kernel_launch(void* const* d_in, const int* in_sizes, int n_in,
                              void* d_out, int out_size, void* d_ws, size_t ws_size,
                              hipStream_t stream){
  const float* x     = (const float*)d_in[0];
  const float* noise = (const float*)d_in[1];
  const float* wi    = (const float*)d_in[2];
  const float* wrec  = (const float*)d_in[3];
  const float* wo    = (const float*)d_in[4];
  float* out = (float*)d_out;

  if (ws_size < (size_t)WS_NEED) return;
  u16* gbuf = (u16*)d_ws;
  unsigned* flags = (unsigned*)((char*)d_ws + STEPFLAG_OFF);

  hipMemsetAsync(d_ws, 0, WS_NEED, stream);   // zero g_0 + flags

  hipFuncSetAttribute((const void*)rnn_kernel,
                      hipFuncAttributeMaxDynamicSharedMemorySize, LDS_BYTES);

  void* args[] = {(void*)&x, (void*)&noise, (void*)&wi, (void*)&wrec, (void*)&wo,
                  (void*)&out, (void*)&gbuf, (void*)&flags};
  hipLaunchCooperativeKernel((const void*)rnn_kernel, dim3(NWG), dim3(256),
                             args, LDS_BYTES, stream);
}

// Round 11
// 3147.954 us; speedup vs baseline: 1.0143x; 1.0109x over previous
//
#include <hip/hip_runtime.h>
#include <hip/hip_bf16.h>

// Leaky tanh RNN, persistent cooperative kernel (round 11: R6 skeleton + out-store
// moved off the pre-flag drain). 8 chains (batch-groups of 8). 128 WGs; WG
// (pid,role) owns col-slice [32r,32r+32) of wrec/wi/wo for chains A=2pid,
// B=2pid+1 (weights LDS-shared). Per half-phase: compute chain C step i while
// chain D's next step is prefetched (early flag poll, g A-frag loads, x@wi
// MFMAs, noise staging). Comm protocol proven in R5/R6: all g/flag ops sc0 sc1
// (MALL coherence point); producer drains stores (vmcnt0) before flag store.
// CHANGE vs R6: w2's out-stores are computed in sec 4 but ISSUED AFTER the
// flag publish as explicit asm stores — their HBM-depth acks retire during the
// next phase instead of gating this phase's drain/barrier.

#define T_ 512
#define I_ 128
#define H_ 1024
#define O_ 64
#define NWG 128
#define POLL_CAP (1<<17)

// workspace
#define GBUF_BYTES (8*2*8*H_*2)          // 262144
#define STEPFLAG_OFF GBUF_BYTES          // u16[8][64] = 1024 B
#define WS_NEED (GBUF_BYTES + 1024)      // 263168 (proven footprint)

// LDS (bf16 element offsets for weights; byte offsets for f32 regions)
#define WREC_HI_E 0
#define WREC_LO_E 32768
#define WI_HI_E   65536
#define WI_LO_E   69632
#define WO_HI_E   73728
#define WO_LO_E   75776
#define RED_OFF_B   155648   // 9 slots * 32 lanes * 16B
#define NSA_OFF_B   160256   // 8*32 f32
#define NSB_OFF_B   161280
#define LDS_BYTES   162304

typedef __bf16 bf16x8 __attribute__((ext_vector_type(8)));
typedef float f32x4 __attribute__((ext_vector_type(4)));
typedef unsigned u32x4 __attribute__((ext_vector_type(4)));
typedef unsigned short u16;

__device__ __forceinline__ float fast_tanh(float v){
  float cx = fminf(fmaxf(v, -14.f), 14.f);
  float e = __builtin_amdgcn_exp2f(cx * 2.8853900817779268f);
  return 1.f - 2.f * __builtin_amdgcn_rcpf(e + 1.f);
}

// ---- system-scope comm primitives (proven in R5/R6) ----
__device__ __forceinline__ void flag_issue(unsigned& v, const u16* p){
  asm volatile("global_load_ushort %0, %1, off sc0 sc1" : "=v"(v) : "v"(p));
}
__device__ __forceinline__ unsigned sflag_load(const u16* p){
  unsigned v;
  asm volatile("global_load_ushort %0, %1, off sc0 sc1\n\ts_waitcnt vmcnt(0)"
               : "=v"(v) : "v"(p) : "memory");
  return v;
}
__device__ __forceinline__ void sflag_store(u16* p, unsigned v){
  asm volatile("global_store_short %0, %1, off sc0 sc1" :: "v"(p), "v"(v) : "memory");
}
__device__ __forceinline__ void g_load_frag(u32x4& d, const u16* p){
  asm volatile("global_load_dwordx4 %0, %1, off sc0 sc1" : "=v"(d) : "v"(p) : "memory");
}
__device__ __forceinline__ void g_store_u16(u16* p, unsigned v){
  asm volatile("global_store_short %0, %1, off sc0 sc1" :: "v"(p), "v"(v) : "memory");
}
__device__ __forceinline__ void g_store_f32(float* p, float v){
  asm volatile("global_store_dword %0, %1, off" :: "v"(p), "v"(v) : "memory");
}
// plain cached input loads (x / noise), asm so vmcnt bookkeeping stays manual
__device__ __forceinline__ void gl_f32x4(f32x4& d, const float* p){
  asm volatile("global_load_dwordx4 %0, %1, off" : "=v"(d) : "v"(p));
}
__device__ __forceinline__ void gl_f32(float& d, const float* p){
  asm volatile("global_load_dword %0, %1, off" : "=v"(d) : "v"(p));
}
// execution barrier + LDS ordering only: does NOT drain vmcnt
__device__ __forceinline__ void barrier_lds(){
  asm volatile("s_waitcnt lgkmcnt(0)\n\ts_barrier" ::: "memory");
}

// [K x 32] col-slice of row-major [K x ld] fp32 -> LDS split bf16 (hi+lo),
// pre-swizzled into MFMA B-frag order (verified rounds 1-8).
__device__ void load_slice(const float* __restrict__ Wg, int ld, int c0, int K,
                           __bf16* hi, __bf16* lo){
  for (int idx = threadIdx.x; idx < K*32; idx += 256){
    int k = idx >> 5, c = idx & 31;
    float v = Wg[(size_t)k*ld + c0 + c];
    __bf16 h = (__bf16)v;
    __bf16 l = (__bf16)(v - (float)h);
    int kt = k >> 5, kin = k & 31, lg = kin >> 3, j = kin & 7;
    int off = (((kt*2 + (c>>4))*64 + (lg*16 + (c&15))) << 3) + j;
    hi[off] = h; lo[off] = l;
  }
}

#define MFMA __builtin_amdgcn_mfma_f32_16x16x32_bf16
#define BC(u) __builtin_bit_cast(bf16x8, u)

struct Chain {
  u32x4 a[8];          // prefetched g A-frags
  f32x4 h0, xA, xB;    // h state, x@wi seeds (hi/lo passes)
  u16 *gg, *gf;
  const u16 *ab;       // per-lane A-frag base into gg
  const float *xb, *nb;
  float *ob;
  float *NS;           // LDS noise stage for this chain
};

// compute chain C step i; prepare chain D step j (j==T_ -> g loads only)
__device__ __forceinline__ void do_half(
    Chain& C, Chain& D, int i, int j,
    __bf16* B, float* RED,
    int lane, int w, int lhalf, int l15, int bf, int wo_off, int c0, int role)
{
  // 1: complete C's g_i A-frag loads (issued during previous half)
  asm volatile("s_waitcnt vmcnt(0)"
    : "+v"(C.a[0]),"+v"(C.a[1]),"+v"(C.a[2]),"+v"(C.a[3]),
      "+v"(C.a[4]),"+v"(C.a[5]),"+v"(C.a[6]),"+v"(C.a[7]) :: "memory");
  __builtin_amdgcn_sched_barrier(0);

  // 1.5: early-issue D's inputs + first flag-poll read (latency hides under C)
  f32x4 xv0,xv1,xv2,xv3,xv4,xv5,xv6,xv7;
  float n0,n1,n2,n3;
  if (j < T_){
    if (w < 2){
      const float* xp = D.xb + ((size_t)(l15 & 7)*T_ + (size_t)j)*I_ + lhalf*8;
      gl_f32x4(xv0, xp);      gl_f32x4(xv1, xp+4);
      gl_f32x4(xv2, xp+32);   gl_f32x4(xv3, xp+36);
      gl_f32x4(xv4, xp+64);   gl_f32x4(xv5, xp+68);
      gl_f32x4(xv6, xp+96);   gl_f32x4(xv7, xp+100);
    } else if (w == 3){
      const int b0 = lane >> 5, cc = lane & 31;
      gl_f32(n0, D.nb + ((size_t)(b0+0)*T_ + j)*H_ + c0 + cc);
      gl_f32(n1, D.nb + ((size_t)(b0+2)*T_ + j)*H_ + c0 + cc);
      gl_f32(n2, D.nb + ((size_t)(b0+4)*T_ + j)*H_ + c0 + cc);
      gl_f32(n3, D.nb + ((size_t)(b0+6)*T_ + j)*H_ + c0 + cc);
    }
  }
  unsigned pv; flag_issue(pv, D.gf + lane);

  // 2: MFMAs for C (wrec hi/lo both halves of slice + wo hi/lo)
  f32x4 c0A={0.f,0.f,0.f,0.f}, c0B={0.f,0.f,0.f,0.f};
  f32x4 c1A={0.f,0.f,0.f,0.f}, c1B={0.f,0.f,0.f,0.f};
  f32x4 oA ={0.f,0.f,0.f,0.f}, oB ={0.f,0.f,0.f,0.f};
  if (w == 0){ c0A = C.xA; c0B = C.xB; }
  if (w == 1){ c1A = C.xA; c1B = C.xB; }
  const int kb = w*8;
  #pragma unroll
  for (int kt = 0; kt < 8; ++kt){
    const int kg = kb + kt;
    bf16x8 bh0 = *(const bf16x8*)(B + WREC_HI_E + kg*1024 + bf);
    bf16x8 bl0 = *(const bf16x8*)(B + WREC_LO_E + kg*1024 + bf);
    bf16x8 bh1 = *(const bf16x8*)(B + WREC_HI_E + kg*1024 + 512 + bf);
    bf16x8 bl1 = *(const bf16x8*)(B + WREC_LO_E + kg*1024 + 512 + bf);
    bf16x8 wh  = *(const bf16x8*)(B + WO_HI_E + wo_off + kg*32);
    bf16x8 wl  = *(const bf16x8*)(B + WO_LO_E + wo_off + kg*32);
    bf16x8 av = BC(C.a[kt]);
    c0A = MFMA(av, bh0, c0A, 0,0,0);  c0B = MFMA(av, bl0, c0B, 0,0,0);
    c1A = MFMA(av, bh1, c1A, 0,0,0);  c1B = MFMA(av, bl1, c1B, 0,0,0);
    oA  = MFMA(av, wh,  oA,  0,0,0);  oB  = MFMA(av, wl,  oB,  0,0,0);
  }
  f32x4 cn0 = c0A + c0B, cn1 = c1A + c1B, co = oA + oB;

  // 3: cross-wave partials
  if (lane < 32){
    if (w == 0){ *(f32x4*)&RED[((1*3+0)*32+lane)*4] = cn1; *(f32x4*)&RED[((2*3+0)*32+lane)*4] = co; }
    if (w == 1){ *(f32x4*)&RED[((0*3+0)*32+lane)*4] = cn0; *(f32x4*)&RED[((2*3+1)*32+lane)*4] = co; }
    if (w == 2){ *(f32x4*)&RED[((0*3+1)*32+lane)*4] = cn0; *(f32x4*)&RED[((1*3+1)*32+lane)*4] = cn1; }
    if (w == 3){ *(f32x4*)&RED[((0*3+2)*32+lane)*4] = cn0; *(f32x4*)&RED[((1*3+2)*32+lane)*4] = cn1; *(f32x4*)&RED[((2*3+2)*32+lane)*4] = co; }
  }
  barrier_lds();

  // 4: owners reduce + h update + store g_{i+1}; w2 COMPUTES out[i-1] (store deferred)
  f32x4 so_out = {0.f,0.f,0.f,0.f};
  bool do_out = false;
  if (w < 2 && lane < 32){
    const int fbase = w ? 3 : 0;
    f32x4 s = w ? cn1 : cn0;
    s += *(f32x4*)&RED[((fbase+0)*32+lane)*4];
    s += *(f32x4*)&RED[((fbase+1)*32+lane)*4];
    s += *(f32x4*)&RED[((fbase+2)*32+lane)*4];
    u16* gp = C.gg + (size_t)((i+1)&1)*(8*H_);
    #pragma unroll
    for (int r = 0; r < 4; ++r){
      int row = lhalf*4 + r;
      float hv = 0.9f*C.h0[r] + 0.1f*s[r] + 0.002f*C.NS[row*32 + w*16 + l15];
      C.h0[r] = hv;
      u16 gv = __builtin_bit_cast(u16, (__bf16)fast_tanh(hv));
      g_store_u16(gp + (size_t)row*H_ + c0 + w*16 + l15, (unsigned)gv);
    }
  }
  if (w == 2 && lane < 32 && i > 0){
    f32x4 s = co;
    s += *(f32x4*)&RED[((2*3+0)*32+lane)*4];
    s += *(f32x4*)&RED[((2*3+1)*32+lane)*4];
    s += *(f32x4*)&RED[((2*3+2)*32+lane)*4];
    so_out = s;
    do_out = (l15 < 2);         // store issued AFTER flag publish (off drain path)
  }

  // drain: g stores reach coherence point; pv + early inputs complete
  if (j < T_ && w < 2){
    asm volatile("s_waitcnt vmcnt(0)"
      : "+v"(pv),"+v"(xv0),"+v"(xv1),"+v"(xv2),"+v"(xv3),
        "+v"(xv4),"+v"(xv5),"+v"(xv6),"+v"(xv7) :: "memory");
  } else if (j < T_ && w == 3){
    asm volatile("s_waitcnt vmcnt(0)"
      : "+v"(pv),"+v"(n0),"+v"(n1),"+v"(n2),"+v"(n3) :: "memory");
  } else {
    asm volatile("s_waitcnt vmcnt(0)" : "+v"(pv) :: "memory");
  }
  __builtin_amdgcn_sched_barrier(0);

  // publish this wave's flag (producer waves only)
  if (w < 2 && lane == 0) sflag_store(C.gf + role*2 + w, (unsigned)(i+1));

  // deferred out[i-1] stores (w2): acks retire during next phase's slack
  if (do_out){
    #pragma unroll
    for (int r = 0; r < 4; ++r){
      int row = lhalf*4 + r;
      g_store_f32(&C.ob[((size_t)row*T_ + (i-1))*O_ + role*2 + l15], so_out[r]);
    }
  }

  // 5: confirm D flags (early read usually suffices), issue D's g_j loads
  {
    const unsigned tgt = (unsigned)j;
    if (!__all((int)(pv >= tgt))){
      int guard = 0;
      while (true){
        unsigned v = sflag_load(D.gf + lane);
        if (__all((int)(v >= tgt))) break;
        if (++guard > POLL_CAP) break;   // bail: wrong answer beats a hang
      }
    }
  }
  {
    const u16* ap = D.ab + (size_t)(j & 1)*(8*H_);
    #pragma unroll
    for (int kt = 0; kt < 8; ++kt) g_load_frag(D.a[kt], ap + kt*32);
  }
  if (j < T_){
    if (w < 2){
      f32x4 nxA = {0.f,0.f,0.f,0.f}, nxB = {0.f,0.f,0.f,0.f};
      #pragma unroll
      for (int kt = 0; kt < 4; ++kt){
        f32x4 v0 = (kt==0)?xv0:(kt==1)?xv2:(kt==2)?xv4:xv6;
        f32x4 v1 = (kt==0)?xv1:(kt==1)?xv3:(kt==2)?xv5:xv7;
        bf16x8 xh, xl;
        #pragma unroll
        for (int jj = 0; jj < 4; ++jj){
          float aa = v0[jj], bb = v1[jj];
          __bf16 ah = (__bf16)aa, bh2 = (__bf16)bb;
          xh[jj] = ah; xh[jj+4] = bh2;
          xl[jj] = (__bf16)(aa - (float)ah); xl[jj+4] = (__bf16)(bb - (float)bh2);
        }
        bf16x8 wih = *(const bf16x8*)(B + WI_HI_E + kt*1024 + w*512 + bf);
        bf16x8 wil = *(const bf16x8*)(B + WI_LO_E + kt*1024 + w*512 + bf);
        nxA = MFMA(xh, wih, nxA, 0,0,0);
        nxB = MFMA(xl, wih, nxB, 0,0,0);
        nxA = MFMA(xh, wil, nxA, 0,0,0);
      }
      D.xA = nxA; D.xB = nxB;
    } else if (w == 3){
      const int b0 = lane >> 5, cc = lane & 31;
      D.NS[(b0+0)*32 + cc] = n0;
      D.NS[(b0+2)*32 + cc] = n1;
      D.NS[(b0+4)*32 + cc] = n2;
      D.NS[(b0+6)*32 + cc] = n3;
    }
  }

  // 6: end-of-half barrier (RED reuse + NS visibility)
  barrier_lds();
}

// prologue prep of chain D step 0 (flags trivially satisfied; g_0 is zeroed)
__device__ __forceinline__ void prep0(Chain& D, __bf16* B,
    int lane, int w, int lhalf, int l15, int bf, int c0)
{
  f32x4 xv0,xv1,xv2,xv3,xv4,xv5,xv6,xv7;
  float n0,n1,n2,n3;
  if (w < 2){
    const float* xp = D.xb + (size_t)(l15 & 7)*T_*I_ + lhalf*8;
    gl_f32x4(xv0, xp);      gl_f32x4(xv1, xp+4);
    gl_f32x4(xv2, xp+32);   gl_f32x4(xv3, xp+36);
    gl_f32x4(xv4, xp+64);   gl_f32x4(xv5, xp+68);
    gl_f32x4(xv6, xp+96);   gl_f32x4(xv7, xp+100);
    asm volatile("s_waitcnt vmcnt(0)"
      : "+v"(xv0),"+v"(xv1),"+v"(xv2),"+v"(xv3),
        "+v"(xv4),"+v"(xv5),"+v"(xv6),"+v"(xv7) :: "memory");
  } else if (w == 3){
    const int b0 = lane >> 5, cc = lane & 31;
    gl_f32(n0, D.nb + (size_t)(b0+0)*T_*H_ + c0 + cc);
    gl_f32(n1, D.nb + (size_t)(b0+2)*T_*H_ + c0 + cc);
    gl_f32(n2, D.nb + (size_t)(b0+4)*T_*H_ + c0 + cc);
    gl_f32(n3, D.nb + (size_t)(b0+6)*T_*H_ + c0 + cc);
    asm volatile("s_waitcnt vmcnt(0)"
      : "+v"(n0),"+v"(n1),"+v"(n2),"+v"(n3) :: "memory");
  }
  __builtin_amdgcn_sched_barrier(0);
  #pragma unroll
  for (int kt = 0; kt < 8; ++kt) g_load_frag(D.a[kt], D.ab + kt*32);
  if (w < 2){
    f32x4 nxA = {0.f,0.f,0.f,0.f}, nxB = {0.f,0.f,0.f,0.f};
    #pragma unroll
    for (int kt = 0; kt < 4; ++kt){
      f32x4 v0 = (kt==0)?xv0:(kt==1)?xv2:(kt==2)?xv4:xv6;
      f32x4 v1 = (kt==0)?xv1:(kt==1)?xv3:(kt==2)?xv5:xv7;
      bf16x8 xh, xl;
      #pragma unroll
      for (int jj = 0; jj < 4; ++jj){
        float aa = v0[jj], bb = v1[jj];
        __bf16 ah = (__bf16)aa, bh2 = (__bf16)bb;
        xh[jj] = ah; xh[jj+4] = bh2;
        xl[jj] = (__bf16)(aa - (float)ah); xl[jj+4] = (__bf16)(bb - (float)bh2);
      }
      bf16x8 wih = *(const bf16x8*)(B + WI_HI_E + kt*1024 + w*512 + bf);
      bf16x8 wil = *(const bf16x8*)(B + WI_LO_E + kt*1024 + w*512 + bf);
      nxA = MFMA(xh, wih, nxA, 0,0,0);
      nxB = MFMA(xl, wih, nxB, 0,0,0);
      nxA = MFMA(xh, wil, nxA, 0,0,0);
    }
    D.xA = nxA; D.xB = nxB;
  } else if (w == 3){
    const int b0 = lane >> 5, cc = lane & 31;
    D.NS[(b0+0)*32 + cc] = n0;
    D.NS[(b0+2)*32 + cc] = n1;
    D.NS[(b0+4)*32 + cc] = n2;
    D.NS[(b0+6)*32 + cc] = n3;
  }
  barrier_lds();
}

// epilogue: out[T-1] = g_T @ wo for chain C (C.a holds g_T frags)
__device__ __forceinline__ void epi(Chain& C, __bf16* B, float* RED,
    int lane, int w, int lhalf, int l15, int bf, int wo_off, int role)
{
  asm volatile("s_waitcnt vmcnt(0)"
    : "+v"(C.a[0]),"+v"(C.a[1]),"+v"(C.a[2]),"+v"(C.a[3]),
      "+v"(C.a[4]),"+v"(C.a[5]),"+v"(C.a[6]),"+v"(C.a[7]) :: "memory");
  __builtin_amdgcn_sched_barrier(0);
  f32x4 oA={0.f,0.f,0.f,0.f}, oB={0.f,0.f,0.f,0.f};
  const int kb = w*8;
  #pragma unroll
  for (int kt = 0; kt < 8; ++kt){
    const int kg = kb + kt;
    bf16x8 wh = *(const bf16x8*)(B + WO_HI_E + wo_off + kg*32);
    bf16x8 wl = *(const bf16x8*)(B + WO_LO_E + wo_off + kg*32);
    bf16x8 av = BC(C.a[kt]);
    oA = MFMA(av, wh, oA, 0,0,0);  oB = MFMA(av, wl, oB, 0,0,0);
  }
  f32x4 co = oA + oB;
  barrier_lds();   // prior RED consumers done
  if (lane < 32){
    if (w == 0) *(f32x4*)&RED[((2*3+0)*32+lane)*4] = co;
    if (w == 1) *(f32x4*)&RED[((2*3+1)*32+lane)*4] = co;
    if (w == 3) *(f32x4*)&RED[((2*3+2)*32+lane)*4] = co;
  }
  barrier_lds();
  if (w == 2 && lane < 32){
    f32x4 s = co;
    s += *(f32x4*)&RED[((2*3+0)*32+lane)*4];
    s += *(f32x4*)&RED[((2*3+1)*32+lane)*4];
    s += *(f32x4*)&RED[((2*3+2)*32+lane)*4];
    if (l15 < 2){
      #pragma unroll
      for (int r = 0; r < 4; ++r){
        int row = lhalf*4 + r;
        C.ob[((size_t)row*T_ + (T_-1))*O_ + role*2 + l15] = s[r];
      }
    }
  }
}

extern "C" __global__ __launch_bounds__(256, 1)
void rnn_kernel(const float* __restrict__ x, const float* __restrict__ noise,
                const float* __restrict__ wi, const float* __restrict__ wrec,
                const float* __restrict__ wo, float* __restrict__ out,
                u16* __restrict__ gbuf, u16* __restrict__ sflags)
{
  extern __shared__ char smem[];
  __bf16* B = (__bf16*)smem;
  float* RED = (float*)(smem + RED_OFF_B);

  const int pid  = blockIdx.x >> 5;
  const int role = blockIdx.x & 31;
  const int c0 = role * 32;

  load_slice(wrec, H_, c0, H_, B + WREC_HI_E, B + WREC_LO_E);
  load_slice(wi,   H_, c0, I_, B + WI_HI_E,  B + WI_LO_E);
  for (int idx = threadIdx.x; idx < 2*H_; idx += 256){
    int col = idx >> 10, k = idx & (H_-1);
    float v = wo[(size_t)k*O_ + role*2 + col];
    __bf16 hh = (__bf16)v;
    B[WO_HI_E + col*H_ + k] = hh;
    B[WO_LO_E + col*H_ + k] = (__bf16)(v - (float)hh);
  }
  __syncthreads();

  const int lane = threadIdx.x & 63;
  const int w    = threadIdx.x >> 6;
  const int lhalf = lane >> 4;
  const int l15   = lane & 15;
  const int bf = lane * 8;
  const int wo_off = (l15 & 1)*1024 + lhalf*8;

  Chain A, Bc;
  const int gA = pid*2, gB = pid*2+1;
  A.gg  = gbuf + gA*(2*8*H_);   A.gf  = sflags + gA*64;
  Bc.gg = gbuf + gB*(2*8*H_);   Bc.gf = sflags + gB*64;
  A.ab  = A.gg  + (size_t)(lane & 7)*H_ + w*256 + lhalf*8;
  Bc.ab = Bc.gg + (size_t)(lane & 7)*H_ + w*256 + lhalf*8;
  A.xb  = x + (size_t)(gA*8)*T_*I_;     Bc.xb = x + (size_t)(gB*8)*T_*I_;
  A.nb  = noise + (size_t)(gA*8)*T_*H_; Bc.nb = noise + (size_t)(gB*8)*T_*H_;
  A.ob  = out + (size_t)(gA*8)*T_*O_;   Bc.ob = out + (size_t)(gB*8)*T_*O_;
  A.NS  = (float*)(smem + NSA_OFF_B);   Bc.NS = (float*)(smem + NSB_OFF_B);
  A.h0  = (f32x4){0.f,0.f,0.f,0.f};     Bc.h0 = (f32x4){0.f,0.f,0.f,0.f};
  A.xA  = (f32x4){0.f,0.f,0.f,0.f};     A.xB  = (f32x4){0.f,0.f,0.f,0.f};
  Bc.xA = (f32x4){0.f,0.f,0.f,0.f};     Bc.xB = (f32x4){0.f,0.f,0.f,0.f};

  prep0(A, B, lane, w, lhalf, l15, bf, c0);

  for (int i = 0; i < T_; ++i){
    do_half(A,  Bc, i, i,   B, RED, lane, w, lhalf, l15, bf, wo_off, c0, role);
    do_half(Bc, A,  i, i+1, B, RED, lane, w, lhalf, l15, bf, wo_off, c0, role);
  }

  epi(A, B, RED, lane, w, lhalf, l15, bf, wo_off, role);
  { // fetch B's g_T (not prefetched) and finish
    int guard = 0;
    while (true){
      unsigned v = sflag_load(Bc.gf + lane);
      if (__all((int)(v >= (unsigned)T_))) break;
      if (++guard > POLL_CAP) break;
    }
    #pragma unroll
    for (int kt = 0; kt < 8; ++kt) g_load_frag(Bc.a[kt], Bc.ab + kt*32); // parity T&1==0
  }
  epi(Bc, B, RED, lane, w, lhalf, l15, bf, wo_off, role);
}

extern "C" void kernel_launch(void* const* d_in, const int* in_sizes, int n_in,
                              void* d_out, int out_size, void* d_ws, size_t ws_size,
                              hipStream_t stream){
  const float* x     = (const float*)d_in[0];
  const float* noise = (const float*)d_in[1];
  const float* wi    = (const float*)d_in[2];
  const float* wrec  = (const float*)d_in[3];
  const float* wo    = (const float*)d_in[4];
  float* out = (float*)d_out;

  if (ws_size < (size_t)WS_NEED) return;
  u16* gbuf = (u16*)d_ws;
  u16* sflags = (u16*)((char*)d_ws + STEPFLAG_OFF);

  hipMemsetAsync(d_ws, 0, WS_NEED, stream);   // zero g_0 + flags

  hipFuncSetAttribute((const void*)rnn_kernel,
                      hipFuncAttributeMaxDynamicSharedMemorySize, LDS_BYTES);

  void* args[] = {(void*)&x, (void*)&noise, (void*)&wi, (void*)&wrec, (void*)&wo,
                  (void*)&out, (void*)&gbuf, (void*)&sflags};
  hipLaunchCooperativeKernel((const void*)rnn_kernel, dim3(NWG), dim3(256),
                             args, LDS_BYTES, stream);
}

// Round 13
// 2872.545 us; speedup vs baseline: 1.1116x; 1.0959x over previous
//
#include <hip/hip_runtime.h>
#include <hip/hip_bf16.h>

// Leaky tanh RNN, persistent cooperative kernel (round 13: R11 skeleton, late
// confirm + early a-load issue, ALL waits vmcnt(0) — no counted vmcnt anywhere).
// Lesson (R9/R10/R12 vs R5-R8/R11): counted vmcnt over a ledger containing
// STORES is unreliable on gfx950 (mixed load/store retirement not FIFO);
// loads-only counted waits or full vmcnt(0) drains are safe. This kernel uses
// only vmcnt(0).
// Structure: 8 chains (batch-groups of 8), 128 WGs; WG (pid,role) owns
// col-slice [32r,32r+32) of wrec/wi/wo for chains A=2pid, B=2pid+1 (LDS).
// Per half-phase: compute chain C step i, prepare chain D step j:
//   1    drain C's a-frags (usually free: producers drained them at 5)
//   1.5  issue D's x/noise loads
//   2    48 MFMAs for C; then issue poll read pv (late sample)
//   2.6  vmcnt(0): retire pv (+xv/+noise) — loads only
//   2.7  confirm D's flags (fast path expected; slow loop = R6 semantics)
//   2.8  issue D's a-loads (long flight from here)
//   3    RED partials + barrier
//   4    owners reduce, h update, g_{i+1} stores; w2 computes out (deferred)
//   5    w<2: vmcnt(0) (g-stores + own a-loads overlap) -> publish flag;
//        seeds MFMA for D. w2: issue deferred out stores. w3: NS writes.
//   6    barrier
// Comm protocol proven R5/R6/R11: all g/flag ops sc0 sc1 (MALL coherence
// point); g-stores drained before flag publish; no fences.

#define T_ 512
#define I_ 128
#define H_ 1024
#define O_ 64
#define NWG 128
#define POLL_CAP (1<<17)

// workspace
#define GBUF_BYTES (8*2*8*H_*2)          // 262144
#define STEPFLAG_OFF GBUF_BYTES          // u16[8][64] = 1024 B
#define WS_NEED (GBUF_BYTES + 1024)      // 263168 (proven footprint)

// LDS (bf16 element offsets for weights; byte offsets for f32 regions)
#define WREC_HI_E 0
#define WREC_LO_E 32768
#define WI_HI_E   65536
#define WI_LO_E   69632
#define WO_HI_E   73728
#define WO_LO_E   75776
#define RED_OFF_B   155648   // 9 slots * 32 lanes * 16B
#define NSA_OFF_B   160256   // 8*32 f32
#define NSB_OFF_B   161280
#define LDS_BYTES   162304

typedef __bf16 bf16x8 __attribute__((ext_vector_type(8)));
typedef float f32x4 __attribute__((ext_vector_type(4)));
typedef unsigned u32x4 __attribute__((ext_vector_type(4)));
typedef unsigned short u16;

__device__ __forceinline__ float fast_tanh(float v){
  float cx = fminf(fmaxf(v, -14.f), 14.f);
  float e = __builtin_amdgcn_exp2f(cx * 2.8853900817779268f);
  return 1.f - 2.f * __builtin_amdgcn_rcpf(e + 1.f);
}

// ---- system-scope comm primitives (proven in R5/R6/R11) ----
__device__ __forceinline__ void flag_issue(unsigned& v, const u16* p){
  asm volatile("global_load_ushort %0, %1, off sc0 sc1" : "=v"(v) : "v"(p));
}
__device__ __forceinline__ unsigned sflag_load(const u16* p){
  unsigned v;
  asm volatile("global_load_ushort %0, %1, off sc0 sc1\n\ts_waitcnt vmcnt(0)"
               : "=v"(v) : "v"(p) : "memory");
  return v;
}
__device__ __forceinline__ void sflag_store(u16* p, unsigned v){
  asm volatile("global_store_short %0, %1, off sc0 sc1" :: "v"(p), "v"(v) : "memory");
}
__device__ __forceinline__ void g_load_frag(u32x4& d, const u16* p){
  asm volatile("global_load_dwordx4 %0, %1, off sc0 sc1" : "=v"(d) : "v"(p) : "memory");
}
__device__ __forceinline__ void g_store_u16(u16* p, unsigned v){
  asm volatile("global_store_short %0, %1, off sc0 sc1" :: "v"(p), "v"(v) : "memory");
}
__device__ __forceinline__ void g_store_f32(float* p, float v){
  asm volatile("global_store_dword %0, %1, off" :: "v"(p), "v"(v) : "memory");
}
// plain cached input loads (x / noise); vmcnt bookkeeping manual
__device__ __forceinline__ void gl_f32x4(f32x4& d, const float* p){
  asm volatile("global_load_dwordx4 %0, %1, off" : "=v"(d) : "v"(p));
}
__device__ __forceinline__ void gl_f32(float& d, const float* p){
  asm volatile("global_load_dword %0, %1, off" : "=v"(d) : "v"(p));
}
// execution barrier + LDS ordering only: does NOT drain vmcnt
__device__ __forceinline__ void barrier_lds(){
  asm volatile("s_waitcnt lgkmcnt(0)\n\ts_barrier" ::: "memory");
}

// [K x 32] col-slice of row-major [K x ld] fp32 -> LDS split bf16 (hi+lo),
// pre-swizzled into MFMA B-frag order (verified rounds 1-8).
__device__ void load_slice(const float* __restrict__ Wg, int ld, int c0, int K,
                           __bf16* hi, __bf16* lo){
  for (int idx = threadIdx.x; idx < K*32; idx += 256){
    int k = idx >> 5, c = idx & 31;
    float v = Wg[(size_t)k*ld + c0 + c];
    __bf16 h = (__bf16)v;
    __bf16 l = (__bf16)(v - (float)h);
    int kt = k >> 5, kin = k & 31, lg = kin >> 3, j = kin & 7;
    int off = (((kt*2 + (c>>4))*64 + (lg*16 + (c&15))) << 3) + j;
    hi[off] = h; lo[off] = l;
  }
}

#define MFMA __builtin_amdgcn_mfma_f32_16x16x32_bf16
#define BC(u) __builtin_bit_cast(bf16x8, u)

struct Chain {
  u32x4 a[8];          // prefetched g A-frags
  f32x4 h0, xA, xB;    // h state, x@wi seeds (hi/lo passes)
  u16 *gg, *gf;
  const u16 *ab;       // per-lane A-frag base into gg
  const float *xb, *nb;
  float *ob;
  float *NS;           // LDS noise stage for this chain
};

// compute chain C step i; prepare chain D step j (j==T_ -> g loads only)
__device__ __forceinline__ void do_half(
    Chain& C, Chain& D, int i, int j,
    __bf16* B, float* RED,
    int lane, int w, int lhalf, int l15, int bf, int wo_off, int c0, int role)
{
  // 1: complete C's g_i A-frag loads (long flight since 2.8 of prev half)
  asm volatile("s_waitcnt vmcnt(0)"
    : "+v"(C.a[0]),"+v"(C.a[1]),"+v"(C.a[2]),"+v"(C.a[3]),
      "+v"(C.a[4]),"+v"(C.a[5]),"+v"(C.a[6]),"+v"(C.a[7]) :: "memory");
  __builtin_amdgcn_sched_barrier(0);

  // 1.5: early-issue D's inputs (latency hides under C's MFMAs)
  f32x4 xv0,xv1,xv2,xv3,xv4,xv5,xv6,xv7;
  float n0,n1,n2,n3;
  if (j < T_){
    if (w < 2){
      const float* xp = D.xb + ((size_t)(l15 & 7)*T_ + (size_t)j)*I_ + lhalf*8;
      gl_f32x4(xv0, xp);      gl_f32x4(xv1, xp+4);
      gl_f32x4(xv2, xp+32);   gl_f32x4(xv3, xp+36);
      gl_f32x4(xv4, xp+64);   gl_f32x4(xv5, xp+68);
      gl_f32x4(xv6, xp+96);   gl_f32x4(xv7, xp+100);
    } else if (w == 3){
      const int b0 = lane >> 5, cc = lane & 31;
      gl_f32(n0, D.nb + ((size_t)(b0+0)*T_ + j)*H_ + c0 + cc);
      gl_f32(n1, D.nb + ((size_t)(b0+2)*T_ + j)*H_ + c0 + cc);
      gl_f32(n2, D.nb + ((size_t)(b0+4)*T_ + j)*H_ + c0 + cc);
      gl_f32(n3, D.nb + ((size_t)(b0+6)*T_ + j)*H_ + c0 + cc);
    }
  }

  // 2: MFMAs for C (wrec hi/lo both halves of slice + wo hi/lo)
  f32x4 c0A={0.f,0.f,0.f,0.f}, c0B={0.f,0.f,0.f,0.f};
  f32x4 c1A={0.f,0.f,0.f,0.f}, c1B={0.f,0.f,0.f,0.f};
  f32x4 oA ={0.f,0.f,0.f,0.f}, oB ={0.f,0.f,0.f,0.f};
  if (w == 0){ c0A = C.xA; c0B = C.xB; }
  if (w == 1){ c1A = C.xA; c1B = C.xB; }
  const int kb = w*8;
  #pragma unroll
  for (int kt = 0; kt < 8; ++kt){
    const int kg = kb + kt;
    bf16x8 bh0 = *(const bf16x8*)(B + WREC_HI_E + kg*1024 + bf);
    bf16x8 bl0 = *(const bf16x8*)(B + WREC_LO_E + kg*1024 + bf);
    bf16x8 bh1 = *(const bf16x8*)(B + WREC_HI_E + kg*1024 + 512 + bf);
    bf16x8 bl1 = *(const bf16x8*)(B + WREC_LO_E + kg*1024 + 512 + bf);
    bf16x8 wh  = *(const bf16x8*)(B + WO_HI_E + wo_off + kg*32);
    bf16x8 wl  = *(const bf16x8*)(B + WO_LO_E + wo_off + kg*32);
    bf16x8 av = BC(C.a[kt]);
    c0A = MFMA(av, bh0, c0A, 0,0,0);  c0B = MFMA(av, bl0, c0B, 0,0,0);
    c1A = MFMA(av, bh1, c1A, 0,0,0);  c1B = MFMA(av, bl1, c1B, 0,0,0);
    oA  = MFMA(av, wh,  oA,  0,0,0);  oB  = MFMA(av, wl,  oB,  0,0,0);
  }
  // 2.5: poll read NOW — samples MALL well after the peers' publish
  unsigned pv; flag_issue(pv, D.gf + lane);

  f32x4 cn0 = c0A + c0B, cn1 = c1A + c1B, co = oA + oB;

  // 2.6: retire pv (+inputs) — LOADS ONLY ledger, full drain (safe)
  if (j < T_ && w < 2){
    asm volatile("s_waitcnt vmcnt(0)"
      : "+v"(pv),"+v"(xv0),"+v"(xv1),"+v"(xv2),"+v"(xv3),
        "+v"(xv4),"+v"(xv5),"+v"(xv6),"+v"(xv7) :: "memory");
  } else if (j < T_ && w == 3){
    asm volatile("s_waitcnt vmcnt(0)"
      : "+v"(pv),"+v"(n0),"+v"(n1),"+v"(n2),"+v"(n3) :: "memory");
  } else {
    asm volatile("s_waitcnt vmcnt(0)" : "+v"(pv) :: "memory");
  }
  __builtin_amdgcn_sched_barrier(0);

  // 2.7: confirm D's flags (fast path expected; slow path = proven R6 loop)
  {
    const unsigned tgt = (unsigned)j;
    if (!__all((int)(pv >= tgt))){
      int guard = 0;
      while (true){
        unsigned v = sflag_load(D.gf + lane);
        if (__all((int)(v >= tgt))) break;
        if (++guard > POLL_CAP) break;   // bail: wrong answer beats a hang
      }
    }
  }
  // 2.8: issue D's a-loads — long flight through sections 3..6
  {
    const u16* ap = D.ab + (size_t)(j & 1)*(8*H_);
    #pragma unroll
    for (int kt = 0; kt < 8; ++kt) g_load_frag(D.a[kt], ap + kt*32);
  }

  // 3: cross-wave partials
  if (lane < 32){
    if (w == 0){ *(f32x4*)&RED[((1*3+0)*32+lane)*4] = cn1; *(f32x4*)&RED[((2*3+0)*32+lane)*4] = co; }
    if (w == 1){ *(f32x4*)&RED[((0*3+0)*32+lane)*4] = cn0; *(f32x4*)&RED[((2*3+1)*32+lane)*4] = co; }
    if (w == 2){ *(f32x4*)&RED[((0*3+1)*32+lane)*4] = cn0; *(f32x4*)&RED[((1*3+1)*32+lane)*4] = cn1; }
    if (w == 3){ *(f32x4*)&RED[((0*3+2)*32+lane)*4] = cn0; *(f32x4*)&RED[((1*3+2)*32+lane)*4] = cn1; *(f32x4*)&RED[((2*3+2)*32+lane)*4] = co; }
  }
  barrier_lds();

  // 4: owners reduce + h update + g_{i+1} stores; w2 computes out[i-1] (deferred)
  f32x4 so_out = {0.f,0.f,0.f,0.f};
  bool do_out = false;
  if (w < 2 && lane < 32){
    const int fbase = w ? 3 : 0;
    f32x4 s = w ? cn1 : cn0;
    s += *(f32x4*)&RED[((fbase+0)*32+lane)*4];
    s += *(f32x4*)&RED[((fbase+1)*32+lane)*4];
    s += *(f32x4*)&RED[((fbase+2)*32+lane)*4];
    u16* gp = C.gg + (size_t)((i+1)&1)*(8*H_);
    #pragma unroll
    for (int r = 0; r < 4; ++r){
      int row = lhalf*4 + r;
      float hv = 0.9f*C.h0[r] + 0.1f*s[r] + 0.002f*C.NS[row*32 + w*16 + l15];
      C.h0[r] = hv;
      u16 gv = __builtin_bit_cast(u16, (__bf16)fast_tanh(hv));
      g_store_u16(gp + (size_t)row*H_ + c0 + w*16 + l15, (unsigned)gv);
    }
  }
  if (w == 2 && lane < 32 && i > 0){
    f32x4 s = co;
    s += *(f32x4*)&RED[((2*3+0)*32+lane)*4];
    s += *(f32x4*)&RED[((2*3+1)*32+lane)*4];
    s += *(f32x4*)&RED[((2*3+2)*32+lane)*4];
    so_out = s;
    do_out = (l15 < 2);
  }

  // 5: producers drain (g-stores + own a-loads overlap in one vmcnt0), publish,
  //    then seed MFMAs for D. w2 issues deferred outs. w3 stages NS.
  if (w < 2){
    asm volatile("s_waitcnt vmcnt(0)" ::: "memory");   // stores at MALL; a-loads done
    if (lane == 0) sflag_store(C.gf + role*2 + w, (unsigned)(i+1));
    if (j < T_){
      f32x4 nxA = {0.f,0.f,0.f,0.f}, nxB = {0.f,0.f,0.f,0.f};
      #pragma unroll
      for (int kt = 0; kt < 4; ++kt){
        f32x4 v0 = (kt==0)?xv0:(kt==1)?xv2:(kt==2)?xv4:xv6;
        f32x4 v1 = (kt==0)?xv1:(kt==1)?xv3:(kt==2)?xv5:xv7;
        bf16x8 xh, xl;
        #pragma unroll
        for (int jj = 0; jj < 4; ++jj){
          float aa = v0[jj], bb = v1[jj];
          __bf16 ah = (__bf16)aa, bh2 = (__bf16)bb;
          xh[jj] = ah; xh[jj+4] = bh2;
          xl[jj] = (__bf16)(aa - (float)ah); xl[jj+4] = (__bf16)(bb - (float)bh2);
        }
        bf16x8 wih = *(const bf16x8*)(B + WI_HI_E + kt*1024 + w*512 + bf);
        bf16x8 wil = *(const bf16x8*)(B + WI_LO_E + kt*1024 + w*512 + bf);
        nxA = MFMA(xh, wih, nxA, 0,0,0);
        nxB = MFMA(xl, wih, nxB, 0,0,0);
        nxA = MFMA(xh, wil, nxA, 0,0,0);
      }
      D.xA = nxA; D.xB = nxB;
    }
  } else if (w == 2){
    if (do_out){
      #pragma unroll
      for (int r = 0; r < 4; ++r){
        int row = lhalf*4 + r;
        g_store_f32(&C.ob[((size_t)row*T_ + (i-1))*O_ + role*2 + l15], so_out[r]);
      }
    }
  } else { // w == 3
    if (j < T_){
      const int b0 = lane >> 5, cc = lane & 31;
      D.NS[(b0+0)*32 + cc] = n0;
      D.NS[(b0+2)*32 + cc] = n1;
      D.NS[(b0+4)*32 + cc] = n2;
      D.NS[(b0+6)*32 + cc] = n3;
    }
  }

  // 6: end-of-half barrier (RED reuse + NS visibility)
  barrier_lds();
}

// prologue prep of chain D step 0 (flags trivially satisfied; g_0 is zeroed)
__device__ __forceinline__ void prep0(Chain& D, __bf16* B,
    int lane, int w, int lhalf, int l15, int bf, int c0)
{
  f32x4 xv0,xv1,xv2,xv3,xv4,xv5,xv6,xv7;
  float n0,n1,n2,n3;
  if (w < 2){
    const float* xp = D.xb + (size_t)(l15 & 7)*T_*I_ + lhalf*8;
    gl_f32x4(xv0, xp);      gl_f32x4(xv1, xp+4);
    gl_f32x4(xv2, xp+32);   gl_f32x4(xv3, xp+36);
    gl_f32x4(xv4, xp+64);   gl_f32x4(xv5, xp+68);
    gl_f32x4(xv6, xp+96);   gl_f32x4(xv7, xp+100);
    asm volatile("s_waitcnt vmcnt(0)"
      : "+v"(xv0),"+v"(xv1),"+v"(xv2),"+v"(xv3),
        "+v"(xv4),"+v"(xv5),"+v"(xv6),"+v"(xv7) :: "memory");
  } else if (w == 3){
    const int b0 = lane >> 5, cc = lane & 31;
    gl_f32(n0, D.nb + (size_t)(b0+0)*T_*H_ + c0 + cc);
    gl_f32(n1, D.nb + (size_t)(b0+2)*T_*H_ + c0 + cc);
    gl_f32(n2, D.nb + (size_t)(b0+4)*T_*H_ + c0 + cc);
    gl_f32(n3, D.nb + (size_t)(b0+6)*T_*H_ + c0 + cc);
    asm volatile("s_waitcnt vmcnt(0)"
      : "+v"(n0),"+v"(n1),"+v"(n2),"+v"(n3) :: "memory");
  }
  __builtin_amdgcn_sched_barrier(0);
  #pragma unroll
  for (int kt = 0; kt < 8; ++kt) g_load_frag(D.a[kt], D.ab + kt*32);
  if (w < 2){
    f32x4 nxA = {0.f,0.f,0.f,0.f}, nxB = {0.f,0.f,0.f,0.f};
    #pragma unroll
    for (int kt = 0; kt < 4; ++kt){
      f32x4 v0 = (kt==0)?xv0:(kt==1)?xv2:(kt==2)?xv4:xv6;
      f32x4 v1 = (kt==0)?xv1:(kt==1)?xv3:(kt==2)?xv5:xv7;
      bf16x8 xh, xl;
      #pragma unroll
      for (int jj = 0; jj < 4; ++jj){
        float aa = v0[jj], bb = v1[jj];
        __bf16 ah = (__bf16)aa, bh2 = (__bf16)bb;
        xh[jj] = ah; xh[jj+4] = bh2;
        xl[jj] = (__bf16)(aa - (float)ah); xl[jj+4] = (__bf16)(bb - (float)bh2);
      }
      bf16x8 wih = *(const bf16x8*)(B + WI_HI_E + kt*1024 + w*512 + bf);
      bf16x8 wil = *(const bf16x8*)(B + WI_LO_E + kt*1024 + w*512 + bf);
      nxA = MFMA(xh, wih, nxA, 0,0,0);
      nxB = MFMA(xl, wih, nxB, 0,0,0);
      nxA = MFMA(xh, wil, nxA, 0,0,0);
    }
    D.xA = nxA; D.xB = nxB;
  } else if (w == 3){
    const int b0 = lane >> 5, cc = lane & 31;
    D.NS[(b0+0)*32 + cc] = n0;
    D.NS[(b0+2)*32 + cc] = n1;
    D.NS[(b0+4)*32 + cc] = n2;
    D.NS[(b0+6)*32 + cc] = n3;
  }
  barrier_lds();
}

// epilogue: out[T-1] = g_T @ wo for chain C (C.a holds g_T frags)
__device__ __forceinline__ void epi(Chain& C, __bf16* B, float* RED,
    int lane, int w, int lhalf, int l15, int bf, int wo_off, int role)
{
  asm volatile("s_waitcnt vmcnt(0)"
    : "+v"(C.a[0]),"+v"(C.a[1]),"+v"(C.a[2]),"+v"(C.a[3]),
      "+v"(C.a[4]),"+v"(C.a[5]),"+v"(C.a[6]),"+v"(C.a[7]) :: "memory");
  __builtin_amdgcn_sched_barrier(0);
  f32x4 oA={0.f,0.f,0.f,0.f}, oB={0.f,0.f,0.f,0.f};
  const int kb = w*8;
  #pragma unroll
  for (int kt = 0; kt < 8; ++kt){
    const int kg = kb + kt;
    bf16x8 wh = *(const bf16x8*)(B + WO_HI_E + wo_off + kg*32);
    bf16x8 wl = *(const bf16x8*)(B + WO_LO_E + wo_off + kg*32);
    bf16x8 av = BC(C.a[kt]);
    oA = MFMA(av, wh, oA, 0,0,0);  oB = MFMA(av, wl, oB, 0,0,0);
  }
  f32x4 co = oA + oB;
  barrier_lds();   // prior RED consumers done
  if (lane < 32){
    if (w == 0) *(f32x4*)&RED[((2*3+0)*32+lane)*4] = co;
    if (w == 1) *(f32x4*)&RED[((2*3+1)*32+lane)*4] = co;
    if (w == 3) *(f32x4*)&RED[((2*3+2)*32+lane)*4] = co;
  }
  barrier_lds();
  if (w == 2 && lane < 32){
    f32x4 s = co;
    s += *(f32x4*)&RED[((2*3+0)*32+lane)*4];
    s += *(f32x4*)&RED[((2*3+1)*32+lane)*4];
    s += *(f32x4*)&RED[((2*3+2)*32+lane)*4];
    if (l15 < 2){
      #pragma unroll
      for (int r = 0; r < 4; ++r){
        int row = lhalf*4 + r;
        C.ob[((size_t)row*T_ + (T_-1))*O_ + role*2 + l15] = s[r];
      }
    }
  }
}

extern "C" __global__ __launch_bounds__(256, 1)
void rnn_kernel(const float* __restrict__ x, const float* __restrict__ noise,
                const float* __restrict__ wi, const float* __restrict__ wrec,
                const float* __restrict__ wo, float* __restrict__ out,
                u16* __restrict__ gbuf, u16* __restrict__ sflags)
{
  extern __shared__ char smem[];
  __bf16* B = (__bf16*)smem;
  float* RED = (float*)(smem + RED_OFF_B);

  const int pid  = blockIdx.x >> 5;
  const int role = blockIdx.x & 31;
  const int c0 = role * 32;

  load_slice(wrec, H_, c0, H_, B + WREC_HI_E, B + WREC_LO_E);
  load_slice(wi,   H_, c0, I_, B + WI_HI_E,  B + WI_LO_E);
  for (int idx = threadIdx.x; idx < 2*H_; idx += 256){
    int col = idx >> 10, k = idx & (H_-1);
    float v = wo[(size_t)k*O_ + role*2 + col];
    __bf16 hh = (__bf16)v;
    B[WO_HI_E + col*H_ + k] = hh;
    B[WO_LO_E + col*H_ + k] = (__bf16)(v - (float)hh);
  }
  __syncthreads();

  const int lane = threadIdx.x & 63;
  const int w    = threadIdx.x >> 6;
  const int lhalf = lane >> 4;
  const int l15   = lane & 15;
  const int bf = lane * 8;
  const int wo_off = (l15 & 1)*1024 + lhalf*8;

  Chain A, Bc;
  const int gA = pid*2, gB = pid*2+1;
  A.gg  = gbuf + gA*(2*8*H_);   A.gf  = sflags + gA*64;
  Bc.gg = gbuf + gB*(2*8*H_);   Bc.gf = sflags + gB*64;
  A.ab  = A.gg  + (size_t)(lane & 7)*H_ + w*256 + lhalf*8;
  Bc.ab = Bc.gg + (size_t)(lane & 7)*H_ + w*256 + lhalf*8;
  A.xb  = x + (size_t)(gA*8)*T_*I_;     Bc.xb = x + (size_t)(gB*8)*T_*I_;
  A.nb  = noise + (size_t)(gA*8)*T_*H_; Bc.nb = noise + (size_t)(gB*8)*T_*H_;
  A.ob  = out + (size_t)(gA*8)*T_*O_;   Bc.ob = out + (size_t)(gB*8)*T_*O_;
  A.NS  = (float*)(smem + NSA_OFF_B);   Bc.NS = (float*)(smem + NSB_OFF_B);
  A.h0  = (f32x4){0.f,0.f,0.f,0.f};     Bc.h0 = (f32x4){0.f,0.f,0.f,0.f};
  A.xA  = (f32x4){0.f,0.f,0.f,0.f};     A.xB  = (f32x4){0.f,0.f,0.f,0.f};
  Bc.xA = (f32x4){0.f,0.f,0.f,0.f};     Bc.xB = (f32x4){0.f,0.f,0.f,0.f};

  prep0(A, B, lane, w, lhalf, l15, bf, c0);

  for (int i = 0; i < T_; ++i){
    do_half(A,  Bc, i, i,   B, RED, lane, w, lhalf, l15, bf, wo_off, c0, role);
    do_half(Bc, A,  i, i+1, B, RED, lane, w, lhalf, l15, bf, wo_off, c0, role);
  }

  epi(A, B, RED, lane, w, lhalf, l15, bf, wo_off, role);
  { // fetch B's g_T (not prefetched) and finish
    int guard = 0;
    while (true){
      unsigned v = sflag_load(Bc.gf + lane);
      if (__all((int)(v >= (unsigned)T_))) break;
      if (++guard > POLL_CAP) break;
    }
    #pragma unroll
    for (int kt = 0; kt < 8; ++kt) g_load_frag(Bc.a[kt], Bc.ab + kt*32); // parity T&1==0
  }
  epi(Bc, B, RED, lane, w, lhalf, l15, bf, wo_off, role);
}

extern "C" void kernel_launch(void* const* d_in, const int* in_sizes, int n_in,
                              void* d_out, int out_size, void* d_ws, size_t ws_size,
                              hipStream_t stream){
  const float* x     = (const float*)d_in[0];
  const float* noise = (const float*)d_in[1];
  const float* wi    = (const float*)d_in[2];
  const float* wrec  = (const float*)d_in[3];
  const float* wo    = (const float*)d_in[4];
  float* out = (float*)d_out;

  if (ws_size < (size_t)WS_NEED) return;
  u16* gbuf = (u16*)d_ws;
  u16* sflags = (u16*)((char*)d_ws + STEPFLAG_OFF);

  hipMemsetAsync(d_ws, 0, WS_NEED, stream);   // zero g_0 + flags

  hipFuncSetAttribute((const void*)rnn_kernel,
                      hipFuncAttributeMaxDynamicSharedMemorySize, LDS_BYTES);

  void* args[] = {(void*)&x, (void*)&noise, (void*)&wi, (void*)&wrec, (void*)&wo,
                  (void*)&out, (void*)&gbuf, (void*)&sflags};
  hipLaunchCooperativeKernel((const void*)rnn_kernel, dim3(NWG), dim3(256),
                             args, LDS_BYTES, stream);
}

// Round 15
// 2776.271 us; speedup vs baseline: 1.1501x; 1.0347x over previous
//
#include <hip/hip_runtime.h>
#include <hip/hip_bf16.h>

// Leaky tanh RNN, persistent cooperative kernel (round 15: merged-M single
// chain = R7 geometry + R13 protocol). 4 groups x 16 batches (batch = pid*16 +
// l15 — full M=16 MFMA rows are real), 32 WGs/group, 128 WGs. WG role r owns
// wrec[:,32r:32r+32) bf16 hi+lo in LDS + wi slice + wo 2 cols; K split across
// 4 waves; cross-wave LDS reduce (R7's REDN/REDO layout, verified).
// One step advances ALL 64 batches (R13's half advanced 32).
// Protocol = R13's proven rules: all g/flag ops sc0 sc1 (MALL coherence
// point); g-stores drained (vmcnt 0) before flag publish; late pv sample;
// confirm BEFORE a-load issue; w2 out-stores deferred past confirm; noise
// loaded one step ahead into producer REGISTERS (no LDS staging -> no race);
// ALL waits are vmcnt(0) — counted vmcnt is banned (R12/R14: any in-flight
// store breaks counted-wait semantics; only loads-only ledgers are FIFO).

#define T_ 512
#define I_ 128
#define H_ 1024
#define O_ 64
#define GRPS 4
#define BG 16
#define NWG 128
#define POLL_CAP (1<<17)

// workspace
#define GBUF_BYTES (GRPS*2*BG*H_*2)      // 262144
#define STEPFLAG_OFF GBUF_BYTES          // u16[4][64] = 512 B
#define WS_NEED (GBUF_BYTES + 1024)      // 263168 (proven footprint)

// LDS (bf16 element offsets for weights; byte offsets for f32 regions) — R7's
#define WREC_HI_E 0
#define WREC_LO_E 32768
#define WI_HI_E   65536
#define WI_LO_E   69632
#define WO_HI_E   73728      // col-major [2][1024]
#define WO_LO_E   75776
#define RED_B     155648     // REDN: [2 nt][3 src][64 lanes][f32x4] = 6144 B
#define REDO_B    161792     // REDO: [3 src][8][f32x4] = 384 B
#define LDS_BYTES 162176

typedef __bf16 bf16x8 __attribute__((ext_vector_type(8)));
typedef float f32x4 __attribute__((ext_vector_type(4)));
typedef unsigned u32x4 __attribute__((ext_vector_type(4)));
typedef unsigned short u16;

__device__ __forceinline__ float fast_tanh(float v){
  float cx = fminf(fmaxf(v, -14.f), 14.f);
  float e = __builtin_amdgcn_exp2f(cx * 2.8853900817779268f);
  return 1.f - 2.f * __builtin_amdgcn_rcpf(e + 1.f);
}

// ---- system-scope comm primitives (proven R5-R13) ----
__device__ __forceinline__ void flag_issue(unsigned& v, const u16* p){
  asm volatile("global_load_ushort %0, %1, off sc0 sc1" : "=v"(v) : "v"(p));
}
__device__ __forceinline__ unsigned sflag_load(const u16* p){
  unsigned v;
  asm volatile("global_load_ushort %0, %1, off sc0 sc1\n\ts_waitcnt vmcnt(0)"
               : "=v"(v) : "v"(p) : "memory");
  return v;
}
__device__ __forceinline__ void sflag_store(u16* p, unsigned v){
  asm volatile("global_store_short %0, %1, off sc0 sc1" :: "v"(p), "v"(v) : "memory");
}
__device__ __forceinline__ void g_load_frag(u32x4& d, const u16* p){
  asm volatile("global_load_dwordx4 %0, %1, off sc0 sc1" : "=v"(d) : "v"(p) : "memory");
}
__device__ __forceinline__ void g_store_u16(u16* p, unsigned v){
  asm volatile("global_store_short %0, %1, off sc0 sc1" :: "v"(p), "v"(v) : "memory");
}
__device__ __forceinline__ void g_store_f32(float* p, float v){
  asm volatile("global_store_dword %0, %1, off" :: "v"(p), "v"(v) : "memory");
}
// plain cached input loads (x / noise); vmcnt bookkeeping manual
__device__ __forceinline__ void gl_f32x4(f32x4& d, const float* p){
  asm volatile("global_load_dwordx4 %0, %1, off" : "=v"(d) : "v"(p));
}
__device__ __forceinline__ void gl_f32(float& d, const float* p){
  asm volatile("global_load_dword %0, %1, off" : "=v"(d) : "v"(p));
}
// execution barrier + LDS ordering only: does NOT drain vmcnt
__device__ __forceinline__ void barrier_lds(){
  asm volatile("s_waitcnt lgkmcnt(0)\n\ts_barrier" ::: "memory");
}

// [K x 32] col-slice of row-major [K x ld] fp32 -> LDS split bf16 (hi+lo),
// pre-swizzled into MFMA B-frag order (verified rounds 1-13).
__device__ void load_slice(const float* __restrict__ Wg, int ld, int c0, int K,
                           __bf16* hi, __bf16* lo){
  for (int idx = threadIdx.x; idx < K*32; idx += 256){
    int k = idx >> 5, c = idx & 31;
    float v = Wg[(size_t)k*ld + c0 + c];
    __bf16 h = (__bf16)v;
    __bf16 l = (__bf16)(v - (float)h);
    int kt = k >> 5, kin = k & 31, lg = kin >> 3, j = kin & 7;
    int off = (((kt*2 + (c>>4))*64 + (lg*16 + (c&15))) << 3) + j;
    hi[off] = h; lo[off] = l;
  }
}

#define MFMA __builtin_amdgcn_mfma_f32_16x16x32_bf16
#define BC(u) __builtin_bit_cast(bf16x8, u)

#define PACKX(v0, v1, xh, xl)                                      \
  { _Pragma("unroll")                                              \
    for (int jj = 0; jj < 4; ++jj){                                \
      float aa = (v0)[jj], bb = (v1)[jj];                          \
      __bf16 ah = (__bf16)aa, bh2 = (__bf16)bb;                    \
      (xh)[jj] = ah; (xh)[jj+4] = bh2;                             \
      (xl)[jj] = (__bf16)(aa - (float)ah);                         \
      (xl)[jj+4] = (__bf16)(bb - (float)bh2); } }

#define SEEDS(OA, OB)                                                          \
  { f32x4 nxA = {0.f,0.f,0.f,0.f}, nxB = {0.f,0.f,0.f,0.f};                    \
    _Pragma("unroll")                                                          \
    for (int kt = 0; kt < 4; ++kt){                                            \
      f32x4 v0 = (kt==0)?xv0:(kt==1)?xv2:(kt==2)?xv4:xv6;                      \
      f32x4 v1 = (kt==0)?xv1:(kt==1)?xv3:(kt==2)?xv5:xv7;                      \
      bf16x8 xh, xl; PACKX(v0, v1, xh, xl);                                    \
      bf16x8 wih = *(const bf16x8*)(B + WI_HI_E + kt*1024 + w*512 + bf);       \
      bf16x8 wil = *(const bf16x8*)(B + WI_LO_E + kt*1024 + w*512 + bf);       \
      nxA = MFMA(xh, wih, nxA, 0,0,0);                                         \
      nxB = MFMA(xl, wih, nxB, 0,0,0);                                         \
      nxA = MFMA(xh, wil, nxA, 0,0,0);                                         \
    }                                                                          \
    OA = nxA; OB = nxB; }

extern "C" __global__ __launch_bounds__(256, 1)
void rnn_kernel(const float* __restrict__ x, const float* __restrict__ noise,
                const float* __restrict__ wi, const float* __restrict__ wrec,
                const float* __restrict__ wo, float* __restrict__ out,
                u16* __restrict__ gbuf, u16* __restrict__ sflags)
{
  extern __shared__ char smem[];
  __bf16* B = (__bf16*)smem;
  float* REDN = (float*)(smem + RED_B);
  float* REDO = (float*)(smem + REDO_B);

  const int grp  = blockIdx.x >> 5;
  const int role = blockIdx.x & 31;
  const int c0 = role * 32;

  load_slice(wrec, H_, c0, H_, B + WREC_HI_E, B + WREC_LO_E);
  load_slice(wi,   H_, c0, I_, B + WI_HI_E,  B + WI_LO_E);
  for (int idx = threadIdx.x; idx < 2*H_; idx += 256){
    int col = idx >> 10, k = idx & (H_-1);
    float v = wo[(size_t)k*O_ + role*2 + col];
    __bf16 hh = (__bf16)v;
    B[WO_HI_E + col*H_ + k] = hh;
    B[WO_LO_E + col*H_ + k] = (__bf16)(v - (float)hh);
  }
  __syncthreads();

  const int lane = threadIdx.x & 63;
  const int w    = threadIdx.x >> 6;   // wave = k-chunk of 256
  const int lhalf = lane >> 4;         // 0..3
  const int l15   = lane & 15;
  const int bf = lane * 8;
  const int wo_off = (l15 & 1)*1024 + lhalf*8;

  u16* gg = gbuf + grp * (2*BG*H_);
  u16* gf = sflags + grp * 64;
  const u16* pollp = gf + lane;        // 64 flags = role*2 + wave(0/1)
  const u16* abase = gg + (size_t)l15*H_ + w*256 + lhalf*8;   // A row = l15 (REAL 16 rows)

  const float* xrow  = x + (size_t)(grp*BG + l15)*T_*I_ + lhalf*8;
  const float* nrow0 = noise + (size_t)(grp*BG + lhalf*4)*T_*H_ + c0 + (w&1)*16 + l15;
  float* orow = out + (size_t)(grp*BG + lhalf*4)*T_*O_ + role*2 + (l15 & 1);

  f32x4 h0 = {0.f,0.f,0.f,0.f};
  f32x4 xA = {0.f,0.f,0.f,0.f}, xB = {0.f,0.f,0.f,0.f};
  u32x4 a[8];
  f32x4 xv0,xv1,xv2,xv3,xv4,xv5,xv6,xv7;
  float nz[4] = {0.f,0.f,0.f,0.f};

  // ---------------- prologue: x_0 seeds + n_0 + g_0 a-loads ----------------
  if (w < 2){
    gl_f32x4(xv0, xrow);      gl_f32x4(xv1, xrow+4);
    gl_f32x4(xv2, xrow+32);   gl_f32x4(xv3, xrow+36);
    gl_f32x4(xv4, xrow+64);   gl_f32x4(xv5, xrow+68);
    gl_f32x4(xv6, xrow+96);   gl_f32x4(xv7, xrow+100);
    gl_f32(nz[0], nrow0);
    gl_f32(nz[1], nrow0 + (size_t)T_*H_);
    gl_f32(nz[2], nrow0 + 2*(size_t)T_*H_);
    gl_f32(nz[3], nrow0 + 3*(size_t)T_*H_);
    asm volatile("s_waitcnt vmcnt(0)"
      : "+v"(xv0),"+v"(xv1),"+v"(xv2),"+v"(xv3),
        "+v"(xv4),"+v"(xv5),"+v"(xv6),"+v"(xv7),
        "+v"(nz[0]),"+v"(nz[1]),"+v"(nz[2]),"+v"(nz[3]) :: "memory");
    __builtin_amdgcn_sched_barrier(0);
    SEEDS(xA, xB);
  }
  #pragma unroll
  for (int kt = 0; kt < 8; ++kt) g_load_frag(a[kt], abase + kt*32);  // g_0 (zeros)
  barrier_lds();

  // ---------------- main loop: one step advances all 64 batches ----------------
  for (int i = 0; i < T_; ++i){
    // 1: drain a-frags (+ any leftover stores from prev step) — vmcnt(0)
    asm volatile("s_waitcnt vmcnt(0)"
      : "+v"(a[0]),"+v"(a[1]),"+v"(a[2]),"+v"(a[3]),
        "+v"(a[4]),"+v"(a[5]),"+v"(a[6]),"+v"(a[7]) :: "memory");
    __builtin_amdgcn_sched_barrier(0);

    // 2: 48 MFMAs (wrec hi/lo both 16-col halves + wo hi/lo)
    f32x4 c0A={0.f,0.f,0.f,0.f}, c0B={0.f,0.f,0.f,0.f};
    f32x4 c1A={0.f,0.f,0.f,0.f}, c1B={0.f,0.f,0.f,0.f};
    f32x4 oA ={0.f,0.f,0.f,0.f}, oB ={0.f,0.f,0.f,0.f};
    if (w == 0){ c0A = xA; c0B = xB; }
    if (w == 1){ c1A = xA; c1B = xB; }
    const int kb = w*8;
    #pragma unroll
    for (int kt = 0; kt < 8; ++kt){
      const int kg = kb + kt;
      bf16x8 bh0 = *(const bf16x8*)(B + WREC_HI_E + kg*1024 + bf);
      bf16x8 bl0 = *(const bf16x8*)(B + WREC_LO_E + kg*1024 + bf);
      bf16x8 bh1 = *(const bf16x8*)(B + WREC_HI_E + kg*1024 + 512 + bf);
      bf16x8 bl1 = *(const bf16x8*)(B + WREC_LO_E + kg*1024 + 512 + bf);
      bf16x8 wh  = *(const bf16x8*)(B + WO_HI_E + wo_off + kg*32);
      bf16x8 wl  = *(const bf16x8*)(B + WO_LO_E + wo_off + kg*32);
      bf16x8 av = BC(a[kt]);
      c0A = MFMA(av, bh0, c0A, 0,0,0);  c0B = MFMA(av, bl0, c0B, 0,0,0);
      c1A = MFMA(av, bh1, c1A, 0,0,0);  c1B = MFMA(av, bl1, c1B, 0,0,0);
      oA  = MFMA(av, wh,  oA,  0,0,0);  oB  = MFMA(av, wl,  oB,  0,0,0);
    }
    f32x4 cn0 = c0A + c0B, cn1 = c1A + c1B, co = oA + oB;

    // 2.5: producers issue next-step inputs (x_{i+1}, n_{i+1})
    float nz2[4] = {0.f,0.f,0.f,0.f};
    const bool more = (i+1 < T_);
    if (w < 2 && more){
      const float* xp = xrow + (size_t)(i+1)*I_;
      gl_f32x4(xv0, xp);      gl_f32x4(xv1, xp+4);
      gl_f32x4(xv2, xp+32);   gl_f32x4(xv3, xp+36);
      gl_f32x4(xv4, xp+64);   gl_f32x4(xv5, xp+68);
      gl_f32x4(xv6, xp+96);   gl_f32x4(xv7, xp+100);
      const float* np = nrow0 + (size_t)(i+1)*H_;
      gl_f32(nz2[0], np);
      gl_f32(nz2[1], np + (size_t)T_*H_);
      gl_f32(nz2[2], np + 2*(size_t)T_*H_);
      gl_f32(nz2[3], np + 3*(size_t)T_*H_);
    }

    // 3: cross-wave partials (R7 layout, all 64 lanes real)
    if (w == 0){ *(f32x4*)&REDN[((1*3+0)*64+lane)*4] = cn1;
                 if (l15 < 2) *(f32x4*)&REDO[(0*8 + lhalf*2 + l15)*4] = co; }
    if (w == 1){ *(f32x4*)&REDN[((0*3+0)*64+lane)*4] = cn0;
                 if (l15 < 2) *(f32x4*)&REDO[(1*8 + lhalf*2 + l15)*4] = co; }
    if (w == 2){ *(f32x4*)&REDN[((0*3+1)*64+lane)*4] = cn0;
                 *(f32x4*)&REDN[((1*3+1)*64+lane)*4] = cn1; }
    if (w == 3){ *(f32x4*)&REDN[((0*3+2)*64+lane)*4] = cn0;
                 *(f32x4*)&REDN[((1*3+2)*64+lane)*4] = cn1;
                 if (l15 < 2) *(f32x4*)&REDO[(2*8 + lhalf*2 + l15)*4] = co; }
    barrier_lds();

    // 4 / 5: role-split tails
    const unsigned tgt = (unsigned)(i+1);
    if (w < 2){
      // reduce own nt-half + h update + g_{i+1} stores (nz already in regs)
      const int fb = w ? 3 : 0;
      f32x4 s = w ? cn1 : cn0;
      s += *(f32x4*)&REDN[((fb+0)*64+lane)*4];
      s += *(f32x4*)&REDN[((fb+1)*64+lane)*4];
      s += *(f32x4*)&REDN[((fb+2)*64+lane)*4];
      u16* gp = gg + (size_t)((i+1)&1)*(BG*H_);
      #pragma unroll
      for (int r = 0; r < 4; ++r){
        int row = lhalf*4 + r;                  // 0..15, all real
        float hv = 0.9f*h0[r] + 0.1f*s[r] + 0.002f*nz[r];
        h0[r] = hv;
        u16 gv = __builtin_bit_cast(u16, (__bf16)fast_tanh(hv));
        g_store_u16(gp + (size_t)row*H_ + c0 + w*16 + l15, (unsigned)gv);
      }
      // 4.5: drain inputs + g-store acks in ONE vmcnt(0)
      if (more){
        asm volatile("s_waitcnt vmcnt(0)"
          : "+v"(xv0),"+v"(xv1),"+v"(xv2),"+v"(xv3),
            "+v"(xv4),"+v"(xv5),"+v"(xv6),"+v"(xv7),
            "+v"(nz2[0]),"+v"(nz2[1]),"+v"(nz2[2]),"+v"(nz2[3]) :: "memory");
      } else {
        asm volatile("s_waitcnt vmcnt(0)" ::: "memory");
      }
      __builtin_amdgcn_sched_barrier(0);
      // publish, then sample pv; overlap pv RT with seed MFMAs
      if (lane == 0) sflag_store(gf + role*2 + w, tgt);
      unsigned pv; flag_issue(pv, pollp);
      if (more){ SEEDS(xA, xB); }
      nz[0]=nz2[0]; nz[1]=nz2[1]; nz[2]=nz2[2]; nz[3]=nz2[3];
      asm volatile("s_waitcnt vmcnt(0)" : "+v"(pv) :: "memory");  // drains flag-store too
      __builtin_amdgcn_sched_barrier(0);
      if (!__all((int)(pv >= tgt))){
        int guard = 0;
        while (true){
          unsigned v = sflag_load(pollp);
          if (__all((int)(v >= tgt))) break;
          if (++guard > POLL_CAP) break;   // bail: wrong answer beats a hang
        }
      }
      { // a-loads for g_{i+1}
        const u16* ap = abase + (size_t)((i+1)&1)*(BG*H_);
        #pragma unroll
        for (int kt = 0; kt < 8; ++kt) g_load_frag(a[kt], ap + kt*32);
      }
    } else if (w == 2){
      f32x4 so = {0.f,0.f,0.f,0.f};
      bool do_out = false;
      if (i > 0){
        f32x4 s = co;
        s += *(f32x4*)&REDO[(0*8 + lhalf*2 + l15)*4];
        s += *(f32x4*)&REDO[(1*8 + lhalf*2 + l15)*4];
        s += *(f32x4*)&REDO[(2*8 + lhalf*2 + l15)*4];
        so = s; do_out = (l15 < 2);
      }
      unsigned pv; flag_issue(pv, pollp);
      asm volatile("s_waitcnt vmcnt(0)" : "+v"(pv) :: "memory");
      __builtin_amdgcn_sched_barrier(0);
      if (!__all((int)(pv >= tgt))){
        int guard = 0;
        while (true){
          unsigned v = sflag_load(pollp);
          if (__all((int)(v >= tgt))) break;
          if (++guard > POLL_CAP) break;
        }
      }
      {
        const u16* ap = abase + (size_t)((i+1)&1)*(BG*H_);
        #pragma unroll
        for (int kt = 0; kt < 8; ++kt) g_load_frag(a[kt], ap + kt*32);
      }
      if (do_out){ // deferred: acks ride to next step's section-1 drain
        #pragma unroll
        for (int r = 0; r < 4; ++r)
          g_store_f32(orow + (size_t)r*T_*O_ + (size_t)(i-1)*O_, so[r]);
      }
    } else { // w3
      unsigned pv; flag_issue(pv, pollp);
      asm volatile("s_waitcnt vmcnt(0)" : "+v"(pv) :: "memory");
      __builtin_amdgcn_sched_barrier(0);
      if (!__all((int)(pv >= tgt))){
        int guard = 0;
        while (true){
          unsigned v = sflag_load(pollp);
          if (__all((int)(v >= tgt))) break;
          if (++guard > POLL_CAP) break;
        }
      }
      {
        const u16* ap = abase + (size_t)((i+1)&1)*(BG*H_);
        #pragma unroll
        for (int kt = 0; kt < 8; ++kt) g_load_frag(a[kt], ap + kt*32);
      }
    }

    // 6: end-of-step barrier (RED/REDO reuse separation)
    barrier_lds();
  }

  // ---------------- epilogue: out[T-1] = g_T @ wo ----------------
  asm volatile("s_waitcnt vmcnt(0)"
    : "+v"(a[0]),"+v"(a[1]),"+v"(a[2]),"+v"(a[3]),
      "+v"(a[4]),"+v"(a[5]),"+v"(a[6]),"+v"(a[7]) :: "memory");
  __builtin_amdgcn_sched_barrier(0);
  {
    f32x4 oA={0.f,0.f,0.f,0.f}, oB={0.f,0.f,0.f,0.f};
    const int kb = w*8;
    #pragma unroll
    for (int kt = 0; kt < 8; ++kt){
      const int kg = kb + kt;
      bf16x8 wh = *(const bf16x8*)(B + WO_HI_E + wo_off + kg*32);
      bf16x8 wl = *(const bf16x8*)(B + WO_LO_E + wo_off + kg*32);
      bf16x8 av = BC(a[kt]);
      oA = MFMA(av, wh, oA, 0,0,0);  oB = MFMA(av, wl, oB, 0,0,0);
    }
    f32x4 co = oA + oB;
    if (l15 < 2){
      if (w == 0) *(f32x4*)&REDO[(0*8 + lhalf*2 + l15)*4] = co;
      if (w == 1) *(f32x4*)&REDO[(1*8 + lhalf*2 + l15)*4] = co;
      if (w == 3) *(f32x4*)&REDO[(2*8 + lhalf*2 + l15)*4] = co;
    }
    barrier_lds();
    if (w == 2 && l15 < 2){
      f32x4 s = co;
      s += *(f32x4*)&REDO[(0*8 + lhalf*2 + l15)*4];
      s += *(f32x4*)&REDO[(1*8 + lhalf*2 + l15)*4];
      s += *(f32x4*)&REDO[(2*8 + lhalf*2 + l15)*4];
      #pragma unroll
      for (int r = 0; r < 4; ++r)
        g_store_f32(orow + (size_t)r*T_*O_ + (size_t)(T_-1)*O_, s[r]);
    }
  }
  asm volatile("s_waitcnt vmcnt(0)" ::: "memory");
}

extern "C" void kernel_launch(void* const* d_in, const int* in_sizes, int n_in,
                              void* d_out, int out_size, void* d_ws, size_t ws_size,
                              hipStream_t stream){
  const float* x     = (const float*)d_in[0];
  const float* noise = (const float*)d_in[1];
  const float* wi    = (const float*)d_in[2];
  const float* wrec  = (const float*)d_in[3];
  const float* wo    = (const float*)d_in[4];
  float* out = (float*)d_out;

  if (ws_size < (size_t)WS_NEED) return;
  u16* gbuf = (u16*)d_ws;
  u16* sflags = (u16*)((char*)d_ws + STEPFLAG_OFF);

  hipMemsetAsync(d_ws, 0, WS_NEED, stream);   // zero g_0 + flags

  hipFuncSetAttribute((const void*)rnn_kernel,
                      hipFuncAttributeMaxDynamicSharedMemorySize, LDS_BYTES);

  void* args[] = {(void*)&x, (void*)&noise, (void*)&wi, (void*)&wrec, (void*)&wo,
                  (void*)&out, (void*)&gbuf, (void*)&sflags};
  hipLaunchCooperativeKernel((const void*)rnn_kernel, dim3(NWG), dim3(256),
                             args, LDS_BYTES, stream);
}